// Round 6
// baseline (1092.407 us; speedup 1.0000x reference)
//
#include <hip/hip_runtime.h>

// ICNN forward-of-gradient: out = 0.5*d(scalar)/dx + 0.5*x
// R2: all GEMMs on bf16 MFMA (16x16x32) with hi/lo split (3-product ~ fp32 accuracy).
// R3: fusion round — u stored in forward, bwd_g+bwd_x merged, final fused, prep fused.
// R5: uniform bwd blocks; a1=2u*ga computed in g-epilogue, overwrites uL in place.
// R7: counted-vmcnt 2-phase — correct but flat (51us): bwd is staging-VOLUME bound
//     (327 MB/dispatch at 6.4 TB/s aggregate = the memory-system ceiling).
// R8: cut staged bytes 40%: g-path 128x128 tiles (A re-read halved); x-path 128xD(128)
//     tiles split over 4 K-quarters (a1/ga read ONCE), partial gx via fp32 atomicAdd,
//     final affine in a separate tiny kernel. Grid 512 = 2/CU, LDS 64KB, vmcnt(8).

#define Bn 8192
#define Dn 128
#define Hn 512
#define Ln 10

constexpr float NS = 0.2f;

typedef __attribute__((ext_vector_type(8))) short short8;   // 8 bf16 = 4 VGPRs (A/B frag)
typedef __attribute__((ext_vector_type(4))) float f32x4;    // C/D frag

typedef const __attribute__((address_space(1))) void GV;
typedef __attribute__((address_space(3))) void LV;

__device__ __forceinline__ void gload16(const void* g, void* l) {
    __builtin_amdgcn_global_load_lds((GV*)g, (LV*)l, 16, 0, 0);
}

template<int N> __device__ __forceinline__ void vmcnt_wait() {
    asm volatile("s_waitcnt vmcnt(%0)" :: "i"(N) : "memory");
}

#define MFMA(acc, a, b) acc = __builtin_amdgcn_mfma_f32_16x16x32_bf16(a, b, acc, 0, 0, 0)

__device__ __forceinline__ unsigned short bf16_rne(float v) {
    unsigned u = __float_as_uint(v);
    u += 0x7FFFu + ((u >> 16) & 1u);
    return (unsigned short)(u >> 16);
}
__device__ __forceinline__ float bf2f(unsigned short h) {
    return __uint_as_float(((unsigned)h) << 16);
}
__device__ __forceinline__ void split2(float v, unsigned short& h, unsigned short& l) {
    h = bf16_rne(v);
    l = bf16_rne(v - bf2f(h));
}

// ---------------- prep kernels ----------------

__global__ __launch_bounds__(256) void split_flat(const float* __restrict__ in,
        unsigned short* __restrict__ hi, unsigned short* __restrict__ lo, int n4) {
    int i = blockIdx.x * 256 + threadIdx.x;
    if (i >= n4) return;
    float4 v = ((const float4*)in)[i];
    ushort4 h, l;
    split2(v.x, h.x, l.x);
    split2(v.y, h.y, l.y);
    split2(v.z, h.z, l.z);
    split2(v.w, h.w, l.w);
    ((ushort4*)hi)[i] = h;
    ((ushort4*)lo)[i] = l;
}

// per-layer: in [R,C] fp32 -> straight split [R,C] hi/lo AND transposed split [C,R] hi/lo
__global__ __launch_bounds__(256) void split_both(const float* __restrict__ in,
        unsigned short* __restrict__ hi, unsigned short* __restrict__ lo,
        unsigned short* __restrict__ thi, unsigned short* __restrict__ tlo,
        int R, int C) {
    __shared__ float t[32][33];
    const size_t off = (size_t)blockIdx.z * R * C;
    const float* src = in + off;
    unsigned short* sh_ = hi + off;
    unsigned short* sl_ = lo + off;
    unsigned short* dh = thi + off;
    unsigned short* dl = tlo + off;
    const int r0 = blockIdx.x * 32, c0 = blockIdx.y * 32;
    const int tr = threadIdx.x >> 5, tc = threadIdx.x & 31;
#pragma unroll
    for (int i = 0; i < 4; ++i) {
        size_t si = (size_t)(r0 + tr + 8 * i) * C + c0 + tc;
        float v = src[si];
        t[tr + 8 * i][tc] = v;
        unsigned short h, l; split2(v, h, l);
        sh_[si] = h; sl_[si] = l;
    }
    __syncthreads();
#pragma unroll
    for (int i = 0; i < 4; ++i) {
        float v = t[tc][tr + 8 * i];
        unsigned short h, l; split2(v, h, l);
        size_t o = (size_t)(c0 + tr + 8 * i) * R + r0 + tc;
        dh[o] = h; dl[o] = l;
    }
}

// ---------------- fwd layer: 128x64 tile, NT, 3-product split (unchanged) ----------------

__global__ __launch_bounds__(256) void fwd_mfma(
    const unsigned short* __restrict__ xh, const unsigned short* __restrict__ xl,
    const unsigned short* __restrict__ zph, const unsigned short* __restrict__ zpl,
    const unsigned short* __restrict__ Wzh, const unsigned short* __restrict__ Wzl,
    const unsigned short* __restrict__ Wqh, const unsigned short* __restrict__ Wql,
    const unsigned short* __restrict__ Wlh, const unsigned short* __restrict__ Wll,
    const float* __restrict__ bl,
    unsigned short* __restrict__ zoh, unsigned short* __restrict__ zol,
    unsigned short* __restrict__ mask16,
    unsigned short* __restrict__ uoh, unsigned short* __restrict__ uol, int hasZ)
{
    __shared__ __align__(16) char smem[32768];
    unsigned short* Ah  = (unsigned short*)smem;            // [128][32]
    unsigned short* Al  = (unsigned short*)(smem + 8192);
    unsigned short* B0h = (unsigned short*)(smem + 16384);  // [64][32]
    unsigned short* B0l = (unsigned short*)(smem + 20480);
    unsigned short* B1h = (unsigned short*)(smem + 24576);
    unsigned short* B1l = (unsigned short*)(smem + 28672);

    const int tid = threadIdx.x;
    const int w = tid >> 6, lane = tid & 63;
    const int lq = lane >> 4, lc = lane & 15;
    const int wm = (w & 1) * 64, wn = (w >> 1) * 32;
    const int row0 = blockIdx.x * 128, col0 = blockIdx.y * 64;
    const int sr = lane >> 2, sk = (lane & 3) * 8;

    f32x4 accz[4][2], accu[4][2], accv[4][2];
#pragma unroll
    for (int i = 0; i < 4; ++i)
#pragma unroll
        for (int j = 0; j < 2; ++j)
#pragma unroll
            for (int r = 0; r < 4; ++r) { accz[i][j][r] = 0.f; accu[i][j][r] = 0.f; accv[i][j][r] = 0.f; }

    if (hasZ) {
        for (int k0 = 0; k0 < Hn; k0 += 32) {
            __syncthreads();
            for (int c = w; c < 8; c += 4) {
                size_t go = (size_t)(row0 + c * 16 + sr) * Hn + k0 + sk;
                gload16(zph + go, Ah + c * 512);
                gload16(zpl + go, Al + c * 512);
            }
            {
                int c = w;
                size_t go = (size_t)(col0 + c * 16 + sr) * Hn + k0 + sk;
                gload16(Wzh + go, B0h + c * 512);
                gload16(Wzl + go, B0l + c * 512);
            }
            __syncthreads();
            short8 ah[4], al[4];
#pragma unroll
            for (int mt = 0; mt < 4; ++mt) {
                int ao = (wm + mt * 16 + lc) * 32 + lq * 8;
                ah[mt] = *(const short8*)(Ah + ao);
                al[mt] = *(const short8*)(Al + ao);
            }
#pragma unroll
            for (int nt = 0; nt < 2; ++nt) {
                int bo = (wn + nt * 16 + lc) * 32 + lq * 8;
                short8 bh = *(const short8*)(B0h + bo);
                short8 bv = *(const short8*)(B0l + bo);
#pragma unroll
                for (int mt = 0; mt < 4; ++mt) {
                    MFMA(accz[mt][nt], ah[mt], bh);
                    MFMA(accz[mt][nt], ah[mt], bv);
                    MFMA(accz[mt][nt], al[mt], bh);
                }
            }
        }
    }

    for (int k0 = 0; k0 < Dn; k0 += 32) {
        __syncthreads();
        for (int c = w; c < 8; c += 4) {
            size_t go = (size_t)(row0 + c * 16 + sr) * Dn + k0 + sk;
            gload16(xh + go, Ah + c * 512);
            gload16(xl + go, Al + c * 512);
        }
        {
            int c = w;
            size_t go = (size_t)(col0 + c * 16 + sr) * Dn + k0 + sk;
            gload16(Wqh + go, B0h + c * 512);
            gload16(Wql + go, B0l + c * 512);
            gload16(Wlh + go, B1h + c * 512);
            gload16(Wll + go, B1l + c * 512);
        }
        __syncthreads();
        short8 ah[4], al[4];
#pragma unroll
        for (int mt = 0; mt < 4; ++mt) {
            int ao = (wm + mt * 16 + lc) * 32 + lq * 8;
            ah[mt] = *(const short8*)(Ah + ao);
            al[mt] = *(const short8*)(Al + ao);
        }
#pragma unroll
        for (int nt = 0; nt < 2; ++nt) {
            int bo = (wn + nt * 16 + lc) * 32 + lq * 8;
            short8 bqh = *(const short8*)(B0h + bo);
            short8 bql = *(const short8*)(B0l + bo);
            short8 blh = *(const short8*)(B1h + bo);
            short8 bll = *(const short8*)(B1l + bo);
#pragma unroll
            for (int mt = 0; mt < 4; ++mt) {
                MFMA(accu[mt][nt], ah[mt], bqh);
                MFMA(accu[mt][nt], ah[mt], bql);
                MFMA(accu[mt][nt], al[mt], bqh);
                MFMA(accv[mt][nt], ah[mt], blh);
                MFMA(accv[mt][nt], ah[mt], bll);
                MFMA(accv[mt][nt], al[mt], blh);
            }
        }
    }

#pragma unroll
    for (int nt = 0; nt < 2; ++nt) {
        const int colb = col0 + wn + nt * 16;
        const int col = colb + lc;
        const float blv = bl[col];
#pragma unroll
        for (int mt = 0; mt < 4; ++mt) {
            const int rowb = row0 + wm + mt * 16;
#pragma unroll
            for (int r = 0; r < 4; ++r) {
                float uq = accu[mt][nt][r];
                float pre = accz[mt][nt][r] + uq * uq + accv[mt][nt][r] + blv;
                bool m = pre >= 0.f;
                unsigned long long bal = __ballot(m);
                if (lc == 0) {
                    int rw = rowb + lq * 4 + r;
                    mask16[(size_t)rw * 32 + (colb >> 4)] =
                        (unsigned short)((bal >> (lq * 16)) & 0xFFFFull);
                }
                float zv = m ? pre : NS * pre;
                unsigned short h, l; split2(zv, h, l);
                size_t o = (size_t)(rowb + lq * 4 + r) * Hn + col;
                zoh[o] = h; zol[o] = l;
                unsigned short uhh, ull; split2(uq, uhh, ull);
                uoh[o] = uhh; uol[o] = ull;
            }
        }
    }
}

// ---------------- merged backward layer kernel (128x128 both paths) ----------------
// blocks [0, nG):      ga_{l-1} = (ga_l @ Wz) o mask'  (128x128 tiles, 64x4 grid),
//                      ALSO overwrites uL slot l-1 in place with a1_{l-1}=2*u*ga.
// blocks [nG, nG+256): gx += a1_l@WqT' + ga_l@WlT'  (128 rows x full D=128 per block,
//                      K split in 4 quarters; 8 iters; fp32 atomicAdd into gx)
// Per iter: STAGE(next) -> vmcnt(8) -> s_barrier -> ds_read+MFMA -> s_barrier.

__global__ __launch_bounds__(256) void bwd_combo(
    const unsigned short* __restrict__ gah, const unsigned short* __restrict__ gal,
    const unsigned short* __restrict__ WzTh, const unsigned short* __restrict__ WzTl,
    const unsigned short* __restrict__ maskprev,
    unsigned short* __restrict__ goh, unsigned short* __restrict__ gol,
    unsigned short* uph, unsigned short* upl,           // u_{l-1} in, a1_{l-1} out (in place)
    const unsigned short* __restrict__ a1h_, const unsigned short* __restrict__ a1l_,
    const unsigned short* __restrict__ WqTh, const unsigned short* __restrict__ WqTl,
    const unsigned short* __restrict__ WlTh, const unsigned short* __restrict__ WlTl,
    float* __restrict__ gx, int nG)
{
    __shared__ __align__(16) char smem[65536];
    const int bid = blockIdx.x;
    const int tid = threadIdx.x;
    const int w = tid >> 6, lane = tid & 63;
    const int lq = lane >> 4, lc = lane & 15;
    const int sr = lane >> 2, sk = (lane & 3) * 8;
    const int wm = (w & 1) * 64, wn = (w >> 1) * 64;

    f32x4 acc[4][4];
#pragma unroll
    for (int i = 0; i < 4; ++i)
#pragma unroll
        for (int j = 0; j < 4; ++j)
#pragma unroll
            for (int r = 0; r < 4; ++r) acc[i][j][r] = 0.f;

    if (bid < nG) {
        // ---------- g path: 128x128, dbuf 2x32KB, 8 loads/thread/iter ----------
        const int row0 = (bid & 63) * 128, col0 = (bid >> 6) * 128;

        // buffer (32KB): Ah[128][32] 8K, Al 8K, Bh[128][32] 8K, Bl 8K
        auto STAGE = [&](int buf, int k0) {
            char* base = smem + buf * 32768;
            unsigned short* Ah = (unsigned short*)base;
            unsigned short* Al = (unsigned short*)(base + 8192);
            unsigned short* Bh = (unsigned short*)(base + 16384);
            unsigned short* Bl = (unsigned short*)(base + 24576);
#pragma unroll
            for (int cc = 0; cc < 2; ++cc) {
                int c = w + cc * 4;
                size_t ga_ = (size_t)(row0 + c * 16 + sr) * Hn + k0 + sk;
                gload16(gah + ga_, Ah + c * 512);
                gload16(gal + ga_, Al + c * 512);
                size_t gb_ = (size_t)(col0 + c * 16 + sr) * Hn + k0 + sk;
                gload16(WzTh + gb_, Bh + c * 512);
                gload16(WzTl + gb_, Bl + c * 512);
            }
        };

        STAGE(0, 0);                       // 8 loads in flight
        int cur = 0;
        for (int it = 0; it < 16; ++it) {
            if (it < 15) {
                STAGE(cur ^ 1, (it + 1) * 32);   // +8 loads (next buffer)
                vmcnt_wait<8>();                  // oldest 8 (cur buffer) landed
            } else {
                vmcnt_wait<0>();
            }
            __builtin_amdgcn_sched_barrier(0);
            __builtin_amdgcn_s_barrier();
            __builtin_amdgcn_sched_barrier(0);
            const char* base = smem + cur * 32768;
            const unsigned short* Ah = (const unsigned short*)base;
            const unsigned short* Al = (const unsigned short*)(base + 8192);
            const unsigned short* Bh = (const unsigned short*)(base + 16384);
            const unsigned short* Bl = (const unsigned short*)(base + 24576);
            short8 ah[4], al[4];
#pragma unroll
            for (int mt = 0; mt < 4; ++mt) {
                int ao = (wm + mt * 16 + lc) * 32 + lq * 8;
                ah[mt] = *(const short8*)(Ah + ao);
                al[mt] = *(const short8*)(Al + ao);
            }
#pragma unroll
            for (int nt = 0; nt < 4; ++nt) {
                int bo = (wn + nt * 16 + lc) * 32 + lq * 8;
                short8 bh = *(const short8*)(Bh + bo);
                short8 bv = *(const short8*)(Bl + bo);
#pragma unroll
                for (int mt = 0; mt < 4; ++mt) {
                    MFMA(acc[mt][nt], ah[mt], bh);
                    MFMA(acc[mt][nt], ah[mt], bv);
                    MFMA(acc[mt][nt], al[mt], bh);
                }
            }
            __builtin_amdgcn_s_barrier();         // reads of cur done; next STAGE may overwrite
            cur ^= 1;
        }

#pragma unroll
        for (int nt = 0; nt < 4; ++nt) {
            const int colb = col0 + wn + nt * 16;
            const int col = colb + lc;
#pragma unroll
            for (int mt = 0; mt < 4; ++mt) {
                const int rowb = row0 + wm + mt * 16;
#pragma unroll
                for (int r = 0; r < 4; ++r) {
                    int row = rowb + lq * 4 + r;
                    unsigned short wbits = maskprev[(size_t)row * 32 + (colb >> 4)];
                    float f = ((wbits >> lc) & 1) ? 1.f : NS;
                    float v = acc[mt][nt][r] * f;
                    unsigned short h, l; split2(v, h, l);
                    size_t o = (size_t)row * Hn + col;
                    goh[o] = h; gol[o] = l;
                    // a1_{l-1} = 2 * u_{l-1} * ga_{l-1}; overwrite u in place (dead after)
                    float uv = bf2f(uph[o]) + bf2f(upl[o]);
                    float a1v = 2.f * uv * v;
                    unsigned short h2, l2; split2(a1v, h2, l2);
                    uph[o] = h2; upl[o] = l2;
                }
            }
        }
    } else {
        // ---------- x path: 128 rows x D=128, K-quarter kq; 8 iters; atomicAdd ----------
        const int t = bid - nG;
        const int row0 = (t >> 2) * 128;
        const int kq = t & 3;

        // buffer (32KB): Ah[128][32] 8K, Al 8K, Bh[128][32] 8K, Bl 8K
        auto STAGE = [&](int buf, int j) {
            const int pass = j >> 2;
            const int k0 = kq * 128 + (j & 3) * 32;
            const unsigned short* Ash = pass ? gah : a1h_;
            const unsigned short* Asl = pass ? gal : a1l_;
            const unsigned short* Bsh = pass ? WlTh : WqTh;
            const unsigned short* Bsl = pass ? WlTl : WqTl;
            char* base = smem + buf * 32768;
            unsigned short* Ah = (unsigned short*)base;
            unsigned short* Al = (unsigned short*)(base + 8192);
            unsigned short* Bh = (unsigned short*)(base + 16384);
            unsigned short* Bl = (unsigned short*)(base + 24576);
#pragma unroll
            for (int cc = 0; cc < 2; ++cc) {
                int c = w + cc * 4;
                size_t ga_ = (size_t)(row0 + c * 16 + sr) * Hn + k0 + sk;
                gload16(Ash + ga_, Ah + c * 512);
                gload16(Asl + ga_, Al + c * 512);
                size_t gb_ = (size_t)(c * 16 + sr) * Hn + k0 + sk;   // col0 = 0 (full D)
                gload16(Bsh + gb_, Bh + c * 512);
                gload16(Bsl + gb_, Bl + c * 512);
            }
        };

        STAGE(0, 0);
        int cur = 0;
        for (int j = 0; j < 8; ++j) {
            if (j < 7) {
                STAGE(cur ^ 1, j + 1);
                vmcnt_wait<8>();
            } else {
                vmcnt_wait<0>();
            }
            __builtin_amdgcn_sched_barrier(0);
            __builtin_amdgcn_s_barrier();
            __builtin_amdgcn_sched_barrier(0);
            const char* base = smem + cur * 32768;
            const unsigned short* Ah = (const unsigned short*)base;
            const unsigned short* Al = (const unsigned short*)(base + 8192);
            const unsigned short* Bh = (const unsigned short*)(base + 16384);
            const unsigned short* Bl = (const unsigned short*)(base + 24576);
            short8 ah[4], al[4];
#pragma unroll
            for (int mt = 0; mt < 4; ++mt) {
                int ao = (wm + mt * 16 + lc) * 32 + lq * 8;
                ah[mt] = *(const short8*)(Ah + ao);
                al[mt] = *(const short8*)(Al + ao);
            }
#pragma unroll
            for (int nt = 0; nt < 4; ++nt) {
                int bo = (wn + nt * 16 + lc) * 32 + lq * 8;
                short8 bh = *(const short8*)(Bh + bo);
                short8 bv = *(const short8*)(Bl + bo);
#pragma unroll
                for (int mt = 0; mt < 4; ++mt) {
                    MFMA(acc[mt][nt], ah[mt], bh);
                    MFMA(acc[mt][nt], ah[mt], bv);
                    MFMA(acc[mt][nt], al[mt], bh);
                }
            }
            __builtin_amdgcn_s_barrier();
            cur ^= 1;
        }

#pragma unroll
        for (int nt = 0; nt < 4; ++nt) {
            const int col = wn + nt * 16 + lc;
#pragma unroll
            for (int mt = 0; mt < 4; ++mt) {
                const int rowb = row0 + wm + mt * 16;
#pragma unroll
                for (int r = 0; r < 4; ++r) {
                    const int row = rowb + lq * 4 + r;
                    atomicAdd(gx + (size_t)row * Dn + col, acc[mt][nt][r]);
                }
            }
        }
    }
}

// ---------------- small kernels ----------------

// ga_9 = wz_out o mask'; a1_9 = 2*u_9*ga_9 overwrites u_9 in place.
__global__ __launch_bounds__(256) void ga_init(
    const float* __restrict__ wz_out, const unsigned short* __restrict__ mask9,
    unsigned short* uh, unsigned short* ul,
    unsigned short* __restrict__ gh, unsigned short* __restrict__ gl)
{
    int i = blockIdx.x * 256 + threadIdx.x;
    int e = i << 2;
    int b = e >> 9, h = e & 511;
    unsigned short wbits = mask9[(size_t)b * 32 + (h >> 4)];
    float4 wv = *(const float4*)(wz_out + h);
    ushort4 u4h = *(const ushort4*)(uh + e);
    ushort4 u4l = *(const ushort4*)(ul + e);
    int sh = h & 15;
    ushort4 oh, ol, qh, ql;
    float f, a;
    f = wv.x * (((wbits >> (sh + 0)) & 1) ? 1.f : NS); split2(f, oh.x, ol.x);
    a = 2.f * (bf2f(u4h.x) + bf2f(u4l.x)) * f; split2(a, qh.x, ql.x);
    f = wv.y * (((wbits >> (sh + 1)) & 1) ? 1.f : NS); split2(f, oh.y, ol.y);
    a = 2.f * (bf2f(u4h.y) + bf2f(u4l.y)) * f; split2(a, qh.y, ql.y);
    f = wv.z * (((wbits >> (sh + 2)) & 1) ? 1.f : NS); split2(f, oh.z, ol.z);
    a = 2.f * (bf2f(u4h.z) + bf2f(u4l.z)) * f; split2(a, qh.z, ql.z);
    f = wv.w * (((wbits >> (sh + 3)) & 1) ? 1.f : NS); split2(f, oh.w, ol.w);
    a = 2.f * (bf2f(u4h.w) + bf2f(u4l.w)) * f; split2(a, qh.w, ql.w);
    *(ushort4*)(gh + e) = oh;
    *(ushort4*)(gl + e) = ol;
    *(ushort4*)(uh + e) = qh;
    *(ushort4*)(ul + e) = ql;
}

__global__ __launch_bounds__(256) void rowdot_kernel(
    const float* __restrict__ x, const float* __restrict__ wq_out, float* __restrict__ s) {
    const int b = blockIdx.x * 4 + (threadIdx.x >> 6);
    const int lane = threadIdx.x & 63;
    float v = x[(size_t)b * Dn + lane] * wq_out[lane] +
              x[(size_t)b * Dn + 64 + lane] * wq_out[64 + lane];
#pragma unroll
    for (int off = 32; off > 0; off >>= 1) v += __shfl_down(v, off, 64);
    if (lane == 0) s[b] = v;
}

// out = 0.5*gx + s*wq_out + 0.5*wl_out + 0.5*x  (gx accumulated in out via atomics)
__global__ __launch_bounds__(256) void final_kernel(
    float* __restrict__ out, const float* __restrict__ x, const float* __restrict__ s,
    const float* __restrict__ wq_out, const float* __restrict__ wl_out) {
    const int i = blockIdx.x * 256 + threadIdx.x;
    const int base = i << 2;
    const int b = base >> 7;
    const int d = base & (Dn - 1);
    float4 g = *(const float4*)(out + base);
    float4 xv = *(const float4*)(x + base);
    float4 wq = *(const float4*)(wq_out + d);
    float4 wl = *(const float4*)(wl_out + d);
    const float sb = s[b];
    float4 o;
    o.x = 0.5f * g.x + sb * wq.x + 0.5f * wl.x + 0.5f * xv.x;
    o.y = 0.5f * g.y + sb * wq.y + 0.5f * wl.y + 0.5f * xv.y;
    o.z = 0.5f * g.z + sb * wq.z + 0.5f * wl.z + 0.5f * xv.z;
    o.w = 0.5f * g.w + sb * wq.w + 0.5f * wl.w + 0.5f * xv.w;
    *(float4*)(out + base) = o;
}

// ---------------- launcher ----------------

extern "C" void kernel_launch(void* const* d_in, const int* in_sizes, int n_in,
                              void* d_out, int out_size, void* d_ws, size_t ws_size,
                              hipStream_t stream) {
    (void)in_sizes; (void)n_in; (void)out_size; (void)ws_size;
    const float* x      = (const float*)d_in[0];
    const float* Wq     = (const float*)d_in[1];
    const float* Wl     = (const float*)d_in[2];
    const float* bl     = (const float*)d_in[3];
    const float* Wz     = (const float*)d_in[4];
    const float* wz_out = (const float*)d_in[5];
    const float* wq_out = (const float*)d_in[6];
    const float* wl_out = (const float*)d_in[7];
    float* out = (float*)d_out;

    char* p = (char*)d_ws;
    #define CARVE(name, bytes) unsigned short* name = (unsigned short*)p; p += (((size_t)(bytes)) + 255) & ~(size_t)255;
    CARVE(xh,  (size_t)Bn*Dn*2)  CARVE(xl,  (size_t)Bn*Dn*2)
    CARVE(Wqh, (size_t)Ln*Hn*Dn*2) CARVE(Wql, (size_t)Ln*Hn*Dn*2)
    CARVE(Wlh, (size_t)Ln*Hn*Dn*2) CARVE(Wll, (size_t)Ln*Hn*Dn*2)
    CARVE(WqTh,(size_t)Ln*Hn*Dn*2) CARVE(WqTl,(size_t)Ln*Hn*Dn*2)
    CARVE(WlTh,(size_t)Ln*Hn*Dn*2) CARVE(WlTl,(size_t)Ln*Hn*Dn*2)
    CARVE(Wzh, (size_t)(Ln-1)*Hn*Hn*2) CARVE(Wzl, (size_t)(Ln-1)*Hn*Hn*2)
    CARVE(WzTh,(size_t)(Ln-1)*Hn*Hn*2) CARVE(WzTl,(size_t)(Ln-1)*Hn*Hn*2)
    CARVE(zAh, (size_t)Bn*Hn*2) CARVE(zAl, (size_t)Bn*Hn*2)
    CARVE(zBh, (size_t)Bn*Hn*2) CARVE(zBl, (size_t)Bn*Hn*2)
    CARVE(uLh, (size_t)Ln*Bn*Hn*2) CARVE(uLl, (size_t)Ln*Bn*Hn*2)   // u_l bf16 hi/lo; a1 overwrites in place
    float* s = (float*)p; p += (size_t)Bn*4;
    unsigned short* mask16 = (unsigned short*)p; p += (size_t)Ln*Bn*32*2;
    #undef CARVE

    // prep: x split + fused weight split/transpose (each weight read once)
    split_flat<<<(Bn*Dn/4 + 255)/256, 256, 0, stream>>>(x, xh, xl, Bn*Dn/4);
    split_both<<<dim3(Hn/32, Dn/32, Ln), 256, 0, stream>>>(Wq, Wqh, Wql, WqTh, WqTl, Hn, Dn);
    split_both<<<dim3(Hn/32, Dn/32, Ln), 256, 0, stream>>>(Wl, Wlh, Wll, WlTh, WlTl, Hn, Dn);
    split_both<<<dim3(Hn/32, Hn/32, Ln-1), 256, 0, stream>>>(Wz, Wzh, Wzl, WzTh, WzTl, Hn, Hn);

    rowdot_kernel<<<Bn/4, 256, 0, stream>>>(x, wq_out, s);
    hipMemsetAsync(out, 0, (size_t)Bn * Dn * sizeof(float), stream);

    const dim3 gF(Bn/128, Hn/64);  // 64 x 8

    // forward: z_l hi/lo in (l even ? zA : zB); u_l stored per layer (bf16 hi/lo)
    fwd_mfma<<<gF, 256, 0, stream>>>(xh, xl, nullptr, nullptr, nullptr, nullptr,
        Wqh, Wql, Wlh, Wll, bl, zAh, zAl, mask16, uLh, uLl, 0);
    for (int l = 1; l < Ln; ++l) {
        const unsigned short* zh  = (l & 1) ? zAh : zBh;
        const unsigned short* zl_ = (l & 1) ? zAl : zBl;
        unsigned short* oh  = (l & 1) ? zBh : zAh;
        unsigned short* ol_ = (l & 1) ? zBl : zAl;
        fwd_mfma<<<gF, 256, 0, stream>>>(xh, xl, zh, zl_,
            Wzh + (size_t)(l-1)*Hn*Hn, Wzl + (size_t)(l-1)*Hn*Hn,
            Wqh + (size_t)l*Hn*Dn, Wql + (size_t)l*Hn*Dn,
            Wlh + (size_t)l*Hn*Dn, Wll + (size_t)l*Hn*Dn,
            bl + (size_t)l*Hn, oh, ol_, mask16 + (size_t)l*Bn*32,
            uLh + (size_t)l*Bn*Hn, uLl + (size_t)l*Bn*Hn, 1);
    }

    // backward: ga_9 -> zA slots; a1_9 overwrites uL slot 9. Ping-pong downward.
    // One merged launch per layer: 256 g-blocks (128x128, l>0) + 256 x-blocks = 512 = 2/CU.
    ga_init<<<(Bn*Hn/4)/256, 256, 0, stream>>>(wz_out, mask16 + (size_t)9*Bn*32,
        uLh + (size_t)9*Bn*Hn, uLl + (size_t)9*Bn*Hn, zAh, zAl);
    for (int l = Ln - 1; l >= 0; --l) {
        int sidx = (Ln - 1 - l) & 1;
        const unsigned short* gh_  = sidx ? zBh : zAh;
        const unsigned short* gl_  = sidx ? zBl : zAl;
        unsigned short* oh   = sidx ? zAh : zBh;
        unsigned short* ol_  = sidx ? zAl : zBl;
        const int nG = (l > 0) ? 256 : 0;
        bwd_combo<<<nG + 256, 256, 0, stream>>>(
            gh_, gl_,
            (l > 0) ? WzTh + (size_t)(l-1)*Hn*Hn : nullptr,
            (l > 0) ? WzTl + (size_t)(l-1)*Hn*Hn : nullptr,
            (l > 0) ? mask16 + (size_t)(l-1)*Bn*32 : nullptr,
            (l > 0) ? oh : nullptr, (l > 0) ? ol_ : nullptr,
            (l > 0) ? uLh + (size_t)(l-1)*Bn*Hn : nullptr,
            (l > 0) ? uLl + (size_t)(l-1)*Bn*Hn : nullptr,
            uLh + (size_t)l*Bn*Hn, uLl + (size_t)l*Bn*Hn,   // a1_l (in-place in uL slot l)
            WqTh + (size_t)l*Dn*Hn, WqTl + (size_t)l*Dn*Hn,
            WlTh + (size_t)l*Dn*Hn, WlTl + (size_t)l*Dn*Hn,
            out, nG);
    }

    final_kernel<<<(Bn*Dn/4)/256, 256, 0, stream>>>(out, x, s, wq_out, wl_out);
}

// Round 7
// 854.232 us; speedup vs baseline: 1.2788x; 1.2788x over previous
//
#include <hip/hip_runtime.h>

// ICNN forward-of-gradient: out = 0.5*d(scalar)/dx + 0.5*x
// R2: all GEMMs on bf16 MFMA (16x16x32) with hi/lo split (3-product ~ fp32 accuracy).
// R3: fusion round — u stored in forward, bwd_g+bwd_x merged, final fused, prep fused.
// R5: uniform bwd blocks; a1=2u*ga computed in g-epilogue, overwrites uL in place.
// R7: counted-vmcnt 2-phase (STAGE(next) -> vmcnt(N) -> barrier -> MFMA -> barrier).
// R8 (FAILED): 128x128 tiles @64KB LDS -> 1 block/CU, latency exposed, 1092us.
// R9: revert to R7; x-path passes merged into one 32-iter loop at 128x64 tiles with
//     g-identical resources (24KB bufs, 6 loads, vmcnt(6)) -> x bytes 131->98MB,
//     grid 640 = 2.5/CU @ 3/CU LDS capacity. l=0 keeps R7 64-row x variant.

#define Bn 8192
#define Dn 128
#define Hn 512
#define Ln 10

constexpr float NS = 0.2f;

typedef __attribute__((ext_vector_type(8))) short short8;   // 8 bf16 = 4 VGPRs (A/B frag)
typedef __attribute__((ext_vector_type(4))) float f32x4;    // C/D frag

typedef const __attribute__((address_space(1))) void GV;
typedef __attribute__((address_space(3))) void LV;

__device__ __forceinline__ void gload16(const void* g, void* l) {
    __builtin_amdgcn_global_load_lds((GV*)g, (LV*)l, 16, 0, 0);
}

template<int N> __device__ __forceinline__ void vmcnt_wait() {
    asm volatile("s_waitcnt vmcnt(%0)" :: "i"(N) : "memory");
}

#define MFMA(acc, a, b) acc = __builtin_amdgcn_mfma_f32_16x16x32_bf16(a, b, acc, 0, 0, 0)

__device__ __forceinline__ unsigned short bf16_rne(float v) {
    unsigned u = __float_as_uint(v);
    u += 0x7FFFu + ((u >> 16) & 1u);
    return (unsigned short)(u >> 16);
}
__device__ __forceinline__ float bf2f(unsigned short h) {
    return __uint_as_float(((unsigned)h) << 16);
}
__device__ __forceinline__ void split2(float v, unsigned short& h, unsigned short& l) {
    h = bf16_rne(v);
    l = bf16_rne(v - bf2f(h));
}

// ---------------- prep kernels ----------------

__global__ __launch_bounds__(256) void split_flat(const float* __restrict__ in,
        unsigned short* __restrict__ hi, unsigned short* __restrict__ lo, int n4) {
    int i = blockIdx.x * 256 + threadIdx.x;
    if (i >= n4) return;
    float4 v = ((const float4*)in)[i];
    ushort4 h, l;
    split2(v.x, h.x, l.x);
    split2(v.y, h.y, l.y);
    split2(v.z, h.z, l.z);
    split2(v.w, h.w, l.w);
    ((ushort4*)hi)[i] = h;
    ((ushort4*)lo)[i] = l;
}

// per-layer: in [R,C] fp32 -> straight split [R,C] hi/lo AND transposed split [C,R] hi/lo
__global__ __launch_bounds__(256) void split_both(const float* __restrict__ in,
        unsigned short* __restrict__ hi, unsigned short* __restrict__ lo,
        unsigned short* __restrict__ thi, unsigned short* __restrict__ tlo,
        int R, int C) {
    __shared__ float t[32][33];
    const size_t off = (size_t)blockIdx.z * R * C;
    const float* src = in + off;
    unsigned short* sh_ = hi + off;
    unsigned short* sl_ = lo + off;
    unsigned short* dh = thi + off;
    unsigned short* dl = tlo + off;
    const int r0 = blockIdx.x * 32, c0 = blockIdx.y * 32;
    const int tr = threadIdx.x >> 5, tc = threadIdx.x & 31;
#pragma unroll
    for (int i = 0; i < 4; ++i) {
        size_t si = (size_t)(r0 + tr + 8 * i) * C + c0 + tc;
        float v = src[si];
        t[tr + 8 * i][tc] = v;
        unsigned short h, l; split2(v, h, l);
        sh_[si] = h; sl_[si] = l;
    }
    __syncthreads();
#pragma unroll
    for (int i = 0; i < 4; ++i) {
        float v = t[tc][tr + 8 * i];
        unsigned short h, l; split2(v, h, l);
        size_t o = (size_t)(c0 + tr + 8 * i) * R + r0 + tc;
        dh[o] = h; dl[o] = l;
    }
}

// ---------------- fwd layer: 128x64 tile, NT, 3-product split (unchanged) ----------------

__global__ __launch_bounds__(256) void fwd_mfma(
    const unsigned short* __restrict__ xh, const unsigned short* __restrict__ xl,
    const unsigned short* __restrict__ zph, const unsigned short* __restrict__ zpl,
    const unsigned short* __restrict__ Wzh, const unsigned short* __restrict__ Wzl,
    const unsigned short* __restrict__ Wqh, const unsigned short* __restrict__ Wql,
    const unsigned short* __restrict__ Wlh, const unsigned short* __restrict__ Wll,
    const float* __restrict__ bl,
    unsigned short* __restrict__ zoh, unsigned short* __restrict__ zol,
    unsigned short* __restrict__ mask16,
    unsigned short* __restrict__ uoh, unsigned short* __restrict__ uol, int hasZ)
{
    __shared__ __align__(16) char smem[32768];
    unsigned short* Ah  = (unsigned short*)smem;            // [128][32]
    unsigned short* Al  = (unsigned short*)(smem + 8192);
    unsigned short* B0h = (unsigned short*)(smem + 16384);  // [64][32]
    unsigned short* B0l = (unsigned short*)(smem + 20480);
    unsigned short* B1h = (unsigned short*)(smem + 24576);
    unsigned short* B1l = (unsigned short*)(smem + 28672);

    const int tid = threadIdx.x;
    const int w = tid >> 6, lane = tid & 63;
    const int lq = lane >> 4, lc = lane & 15;
    const int wm = (w & 1) * 64, wn = (w >> 1) * 32;
    const int row0 = blockIdx.x * 128, col0 = blockIdx.y * 64;
    const int sr = lane >> 2, sk = (lane & 3) * 8;

    f32x4 accz[4][2], accu[4][2], accv[4][2];
#pragma unroll
    for (int i = 0; i < 4; ++i)
#pragma unroll
        for (int j = 0; j < 2; ++j)
#pragma unroll
            for (int r = 0; r < 4; ++r) { accz[i][j][r] = 0.f; accu[i][j][r] = 0.f; accv[i][j][r] = 0.f; }

    if (hasZ) {
        for (int k0 = 0; k0 < Hn; k0 += 32) {
            __syncthreads();
            for (int c = w; c < 8; c += 4) {
                size_t go = (size_t)(row0 + c * 16 + sr) * Hn + k0 + sk;
                gload16(zph + go, Ah + c * 512);
                gload16(zpl + go, Al + c * 512);
            }
            {
                int c = w;
                size_t go = (size_t)(col0 + c * 16 + sr) * Hn + k0 + sk;
                gload16(Wzh + go, B0h + c * 512);
                gload16(Wzl + go, B0l + c * 512);
            }
            __syncthreads();
            short8 ah[4], al[4];
#pragma unroll
            for (int mt = 0; mt < 4; ++mt) {
                int ao = (wm + mt * 16 + lc) * 32 + lq * 8;
                ah[mt] = *(const short8*)(Ah + ao);
                al[mt] = *(const short8*)(Al + ao);
            }
#pragma unroll
            for (int nt = 0; nt < 2; ++nt) {
                int bo = (wn + nt * 16 + lc) * 32 + lq * 8;
                short8 bh = *(const short8*)(B0h + bo);
                short8 bv = *(const short8*)(B0l + bo);
#pragma unroll
                for (int mt = 0; mt < 4; ++mt) {
                    MFMA(accz[mt][nt], ah[mt], bh);
                    MFMA(accz[mt][nt], ah[mt], bv);
                    MFMA(accz[mt][nt], al[mt], bh);
                }
            }
        }
    }

    for (int k0 = 0; k0 < Dn; k0 += 32) {
        __syncthreads();
        for (int c = w; c < 8; c += 4) {
            size_t go = (size_t)(row0 + c * 16 + sr) * Dn + k0 + sk;
            gload16(xh + go, Ah + c * 512);
            gload16(xl + go, Al + c * 512);
        }
        {
            int c = w;
            size_t go = (size_t)(col0 + c * 16 + sr) * Dn + k0 + sk;
            gload16(Wqh + go, B0h + c * 512);
            gload16(Wql + go, B0l + c * 512);
            gload16(Wlh + go, B1h + c * 512);
            gload16(Wll + go, B1l + c * 512);
        }
        __syncthreads();
        short8 ah[4], al[4];
#pragma unroll
        for (int mt = 0; mt < 4; ++mt) {
            int ao = (wm + mt * 16 + lc) * 32 + lq * 8;
            ah[mt] = *(const short8*)(Ah + ao);
            al[mt] = *(const short8*)(Al + ao);
        }
#pragma unroll
        for (int nt = 0; nt < 2; ++nt) {
            int bo = (wn + nt * 16 + lc) * 32 + lq * 8;
            short8 bqh = *(const short8*)(B0h + bo);
            short8 bql = *(const short8*)(B0l + bo);
            short8 blh = *(const short8*)(B1h + bo);
            short8 bll = *(const short8*)(B1l + bo);
#pragma unroll
            for (int mt = 0; mt < 4; ++mt) {
                MFMA(accu[mt][nt], ah[mt], bqh);
                MFMA(accu[mt][nt], ah[mt], bql);
                MFMA(accu[mt][nt], al[mt], bqh);
                MFMA(accv[mt][nt], ah[mt], blh);
                MFMA(accv[mt][nt], ah[mt], bll);
                MFMA(accv[mt][nt], al[mt], blh);
            }
        }
    }

#pragma unroll
    for (int nt = 0; nt < 2; ++nt) {
        const int colb = col0 + wn + nt * 16;
        const int col = colb + lc;
        const float blv = bl[col];
#pragma unroll
        for (int mt = 0; mt < 4; ++mt) {
            const int rowb = row0 + wm + mt * 16;
#pragma unroll
            for (int r = 0; r < 4; ++r) {
                float uq = accu[mt][nt][r];
                float pre = accz[mt][nt][r] + uq * uq + accv[mt][nt][r] + blv;
                bool m = pre >= 0.f;
                unsigned long long bal = __ballot(m);
                if (lc == 0) {
                    int rw = rowb + lq * 4 + r;
                    mask16[(size_t)rw * 32 + (colb >> 4)] =
                        (unsigned short)((bal >> (lq * 16)) & 0xFFFFull);
                }
                float zv = m ? pre : NS * pre;
                unsigned short h, l; split2(zv, h, l);
                size_t o = (size_t)(rowb + lq * 4 + r) * Hn + col;
                zoh[o] = h; zol[o] = l;
                unsigned short uhh, ull; split2(uq, uhh, ull);
                uoh[o] = uhh; uol[o] = ull;
            }
        }
    }
}

// ---------------- merged backward layer kernel (counted-vmcnt 2-phase) ----------------
// blocks [0, nG):   ga_{l-1} = (ga_l @ Wz) o mask'  (128x64 tiles, dbuf 2x24KB),
//                   ALSO overwrites uL slot l-1 in place with a1_{l-1}=2*u*ga.
// blocks [nG, ..):  gx = a1_l@WqT' + ga_l@WlT'
//                   x128=1: 128x64 tiles, 32-iter merged-pass loop, dbuf 2x24KB (l>0)
//                   x128=0: 64x64 tiles, 32-iter merged-pass loop, dbuf 2x16KB (l=0)
// Per iter: STAGE(next) -> vmcnt(N just-issued) -> s_barrier -> ds_read+MFMA -> s_barrier.
// finalF: fuse out = 0.5*(gx+acc) + s*wq_out + 0.5*wl_out + 0.5*x

__global__ __launch_bounds__(256) void bwd_combo(
    const unsigned short* __restrict__ gah, const unsigned short* __restrict__ gal,
    const unsigned short* __restrict__ WzTh, const unsigned short* __restrict__ WzTl,
    const unsigned short* __restrict__ maskprev,
    unsigned short* __restrict__ goh, unsigned short* __restrict__ gol,
    unsigned short* uph, unsigned short* upl,           // u_{l-1} in, a1_{l-1} out (in place)
    const unsigned short* __restrict__ a1h_, const unsigned short* __restrict__ a1l_,
    const unsigned short* __restrict__ WqTh, const unsigned short* __restrict__ WqTl,
    const unsigned short* __restrict__ WlTh, const unsigned short* __restrict__ WlTl,
    float* __restrict__ gx, int addTo, int nG, int finalF, int x128,
    const float* __restrict__ xin, const float* __restrict__ s,
    const float* __restrict__ wq_out, const float* __restrict__ wl_out)
{
    __shared__ __align__(16) char smem[49152];
    const int bid = blockIdx.x;
    const int tid = threadIdx.x;
    const int w = tid >> 6, lane = tid & 63;
    const int lq = lane >> 4, lc = lane & 15;
    const int sr = lane >> 2, sk = (lane & 3) * 8;

    if (bid < nG) {
        // ---------- g path: 128x64, dbuf 2x24KB, 6 loads/thread/iter ----------
        const int wm = (w & 1) * 64, wn = (w >> 1) * 32;
        const int row0 = (bid & 63) * 128, col0 = (bid >> 6) * 64;

        f32x4 acc[4][2];
#pragma unroll
        for (int i = 0; i < 4; ++i)
#pragma unroll
            for (int j = 0; j < 2; ++j)
#pragma unroll
                for (int r = 0; r < 4; ++r) acc[i][j][r] = 0.f;

        // buffer (24KB): Ah[128][32] 8K, Al 8K, Bh[64][32] 4K, Bl 4K
        auto STAGE = [&](int buf, int k0) {
            char* base = smem + buf * 24576;
            unsigned short* Ah = (unsigned short*)base;
            unsigned short* Al = (unsigned short*)(base + 8192);
            unsigned short* Bh = (unsigned short*)(base + 16384);
            unsigned short* Bl = (unsigned short*)(base + 20480);
#pragma unroll
            for (int c0c = 0; c0c < 2; ++c0c) {
                int c = w + c0c * 4;
                size_t go = (size_t)(row0 + c * 16 + sr) * Hn + k0 + sk;
                gload16(gah + go, Ah + c * 512);
                gload16(gal + go, Al + c * 512);
            }
            {
                int c = w;
                size_t go = (size_t)(col0 + c * 16 + sr) * Hn + k0 + sk;
                gload16(WzTh + go, Bh + c * 512);
                gload16(WzTl + go, Bl + c * 512);
            }
        };

        STAGE(0, 0);                       // 6 loads in flight
        int cur = 0;
        for (int it = 0; it < 16; ++it) {
            if (it < 15) {
                STAGE(cur ^ 1, (it + 1) * 32);   // +6 loads (next buffer)
                vmcnt_wait<6>();                  // oldest 6 (cur buffer) landed
            } else {
                vmcnt_wait<0>();
            }
            __builtin_amdgcn_sched_barrier(0);
            __builtin_amdgcn_s_barrier();         // cur buffer valid for all waves
            __builtin_amdgcn_sched_barrier(0);
            const char* base = smem + cur * 24576;
            const unsigned short* Ah = (const unsigned short*)base;
            const unsigned short* Al = (const unsigned short*)(base + 8192);
            const unsigned short* Bh = (const unsigned short*)(base + 16384);
            const unsigned short* Bl = (const unsigned short*)(base + 20480);
            short8 ah[4], al[4];
#pragma unroll
            for (int mt = 0; mt < 4; ++mt) {
                int ao = (wm + mt * 16 + lc) * 32 + lq * 8;
                ah[mt] = *(const short8*)(Ah + ao);
                al[mt] = *(const short8*)(Al + ao);
            }
#pragma unroll
            for (int nt = 0; nt < 2; ++nt) {
                int bo = (wn + nt * 16 + lc) * 32 + lq * 8;
                short8 bh = *(const short8*)(Bh + bo);
                short8 bv = *(const short8*)(Bl + bo);
#pragma unroll
                for (int mt = 0; mt < 4; ++mt) {
                    MFMA(acc[mt][nt], ah[mt], bh);
                    MFMA(acc[mt][nt], ah[mt], bv);
                    MFMA(acc[mt][nt], al[mt], bh);
                }
            }
            __builtin_amdgcn_s_barrier();         // reads of cur done; next STAGE may overwrite
            cur ^= 1;
        }

#pragma unroll
        for (int nt = 0; nt < 2; ++nt) {
            const int colb = col0 + wn + nt * 16;
            const int col = colb + lc;
#pragma unroll
            for (int mt = 0; mt < 4; ++mt) {
                const int rowb = row0 + wm + mt * 16;
#pragma unroll
                for (int r = 0; r < 4; ++r) {
                    int row = rowb + lq * 4 + r;
                    unsigned short wbits = maskprev[(size_t)row * 32 + (colb >> 4)];
                    float f = ((wbits >> lc) & 1) ? 1.f : NS;
                    float v = acc[mt][nt][r] * f;
                    unsigned short h, l; split2(v, h, l);
                    size_t o = (size_t)row * Hn + col;
                    goh[o] = h; gol[o] = l;
                    // a1_{l-1} = 2 * u_{l-1} * ga_{l-1}; overwrite u in place (dead after)
                    float uv = bf2f(uph[o]) + bf2f(upl[o]);
                    float a1v = 2.f * uv * v;
                    unsigned short h2, l2; split2(a1v, h2, l2);
                    uph[o] = h2; upl[o] = l2;
                }
            }
        }
    } else if (x128) {
        // ---------- x path (l>0): 128x64, merged passes, dbuf 2x24KB, 6 loads/iter ----------
        const int wm = (w & 1) * 64, wn = (w >> 1) * 32;
        const int t = bid - nG;
        const int row0 = (t >> 1) * 128, col0 = (t & 1) * 64;

        f32x4 acc[4][2];
#pragma unroll
        for (int i = 0; i < 4; ++i)
#pragma unroll
            for (int j = 0; j < 2; ++j)
#pragma unroll
                for (int r = 0; r < 4; ++r) acc[i][j][r] = 0.f;

        // buffer (24KB): Ah[128][32] 8K, Al 8K, Bh[64][32] 4K, Bl 4K
        auto STAGE = [&](int buf, int j) {
            const int pass = j >> 4, k0 = (j & 15) * 32;
            const unsigned short* Ash = pass ? gah : a1h_;
            const unsigned short* Asl = pass ? gal : a1l_;
            const unsigned short* Bsh = pass ? WlTh : WqTh;
            const unsigned short* Bsl = pass ? WlTl : WqTl;
            char* base = smem + buf * 24576;
            unsigned short* Ah = (unsigned short*)base;
            unsigned short* Al = (unsigned short*)(base + 8192);
            unsigned short* Bh = (unsigned short*)(base + 16384);
            unsigned short* Bl = (unsigned short*)(base + 20480);
#pragma unroll
            for (int c0c = 0; c0c < 2; ++c0c) {
                int c = w + c0c * 4;
                size_t ga_ = (size_t)(row0 + c * 16 + sr) * Hn + k0 + sk;
                gload16(Ash + ga_, Ah + c * 512);
                gload16(Asl + ga_, Al + c * 512);
            }
            {
                int c = w;
                size_t gb_ = (size_t)(col0 + c * 16 + sr) * Hn + k0 + sk;
                gload16(Bsh + gb_, Bh + c * 512);
                gload16(Bsl + gb_, Bl + c * 512);
            }
        };

        STAGE(0, 0);
        int cur = 0;
        for (int j = 0; j < 32; ++j) {
            if (j < 31) {
                STAGE(cur ^ 1, j + 1);
                vmcnt_wait<6>();
            } else {
                vmcnt_wait<0>();
            }
            __builtin_amdgcn_sched_barrier(0);
            __builtin_amdgcn_s_barrier();
            __builtin_amdgcn_sched_barrier(0);
            const char* base = smem + cur * 24576;
            const unsigned short* Ah = (const unsigned short*)base;
            const unsigned short* Al = (const unsigned short*)(base + 8192);
            const unsigned short* Bh = (const unsigned short*)(base + 16384);
            const unsigned short* Bl = (const unsigned short*)(base + 20480);
            short8 ah[4], al[4];
#pragma unroll
            for (int mt = 0; mt < 4; ++mt) {
                int ao = (wm + mt * 16 + lc) * 32 + lq * 8;
                ah[mt] = *(const short8*)(Ah + ao);
                al[mt] = *(const short8*)(Al + ao);
            }
#pragma unroll
            for (int nt = 0; nt < 2; ++nt) {
                int bo = (wn + nt * 16 + lc) * 32 + lq * 8;
                short8 bh = *(const short8*)(Bh + bo);
                short8 bv = *(const short8*)(Bl + bo);
#pragma unroll
                for (int mt = 0; mt < 4; ++mt) {
                    MFMA(acc[mt][nt], ah[mt], bh);
                    MFMA(acc[mt][nt], ah[mt], bv);
                    MFMA(acc[mt][nt], al[mt], bh);
                }
            }
            __builtin_amdgcn_s_barrier();
            cur ^= 1;
        }

#pragma unroll
        for (int nt = 0; nt < 2; ++nt) {
            const int col = col0 + wn + nt * 16 + lc;
#pragma unroll
            for (int mt = 0; mt < 4; ++mt) {
                const int rowb = row0 + wm + mt * 16;
#pragma unroll
                for (int r = 0; r < 4; ++r) {
                    const int row = rowb + lq * 4 + r;
                    size_t o = (size_t)row * Dn + col;
                    float v = acc[mt][nt][r];
                    if (addTo) v += gx[o];
                    if (finalF) {
                        v = 0.5f * v + s[row] * wq_out[col] + 0.5f * wl_out[col]
                            + 0.5f * xin[o];
                    }
                    gx[o] = v;
                }
            }
        }
    } else {
        // ---------- x path (l=0): 64x64, merged passes, dbuf 2x16KB, 4 loads/iter ----------
        const int wm = (w & 1) * 32, wn = (w >> 1) * 32;
        const int t = bid - nG;
        const int row0 = (t >> 1) * 64, col0 = (t & 1) * 64;

        f32x4 acc[2][2];
#pragma unroll
        for (int i = 0; i < 2; ++i)
#pragma unroll
            for (int j = 0; j < 2; ++j)
#pragma unroll
                for (int r = 0; r < 4; ++r) acc[i][j][r] = 0.f;

        // buffer (16KB): Ah[64][32] 4K, Al 4K, Bh[64][32] 4K, Bl 4K
        auto STAGE = [&](int buf, int j) {
            int pass = j >> 4, k0 = (j & 15) * 32;
            const unsigned short* Ash = pass ? gah : a1h_;
            const unsigned short* Asl = pass ? gal : a1l_;
            const unsigned short* Bsh = pass ? WlTh : WqTh;
            const unsigned short* Bsl = pass ? WlTl : WqTl;
            char* base = smem + buf * 16384;
            unsigned short* Ah = (unsigned short*)base;
            unsigned short* Al = (unsigned short*)(base + 4096);
            unsigned short* Bh = (unsigned short*)(base + 8192);
            unsigned short* Bl = (unsigned short*)(base + 12288);
            int c = w;
            size_t ga_ = (size_t)(row0 + c * 16 + sr) * Hn + k0 + sk;
            gload16(Ash + ga_, Ah + c * 512);
            gload16(Asl + ga_, Al + c * 512);
            size_t gb_ = (size_t)(col0 + c * 16 + sr) * Hn + k0 + sk;
            gload16(Bsh + gb_, Bh + c * 512);
            gload16(Bsl + gb_, Bl + c * 512);
        };

        STAGE(0, 0);
        int cur = 0;
        for (int j = 0; j < 32; ++j) {
            if (j < 31) {
                STAGE(cur ^ 1, j + 1);
                vmcnt_wait<4>();
            } else {
                vmcnt_wait<0>();
            }
            __builtin_amdgcn_sched_barrier(0);
            __builtin_amdgcn_s_barrier();
            __builtin_amdgcn_sched_barrier(0);
            const char* base = smem + cur * 16384;
            const unsigned short* Ah = (const unsigned short*)base;
            const unsigned short* Al = (const unsigned short*)(base + 4096);
            const unsigned short* Bh = (const unsigned short*)(base + 8192);
            const unsigned short* Bl = (const unsigned short*)(base + 12288);
            short8 ah[2], al[2];
#pragma unroll
            for (int mt = 0; mt < 2; ++mt) {
                int ao = (wm + mt * 16 + lc) * 32 + lq * 8;
                ah[mt] = *(const short8*)(Ah + ao);
                al[mt] = *(const short8*)(Al + ao);
            }
#pragma unroll
            for (int nt = 0; nt < 2; ++nt) {
                int bo = (wn + nt * 16 + lc) * 32 + lq * 8;
                short8 bh = *(const short8*)(Bh + bo);
                short8 bv = *(const short8*)(Bl + bo);
#pragma unroll
                for (int mt = 0; mt < 2; ++mt) {
                    MFMA(acc[mt][nt], ah[mt], bh);
                    MFMA(acc[mt][nt], ah[mt], bv);
                    MFMA(acc[mt][nt], al[mt], bh);
                }
            }
            __builtin_amdgcn_s_barrier();
            cur ^= 1;
        }

#pragma unroll
        for (int nt = 0; nt < 2; ++nt) {
            const int col = col0 + wn + nt * 16 + lc;
#pragma unroll
            for (int mt = 0; mt < 2; ++mt) {
                const int rowb = row0 + wm + mt * 16;
#pragma unroll
                for (int r = 0; r < 4; ++r) {
                    const int row = rowb + lq * 4 + r;
                    size_t o = (size_t)row * Dn + col;
                    float v = acc[mt][nt][r];
                    if (addTo) v += gx[o];
                    if (finalF) {
                        v = 0.5f * v + s[row] * wq_out[col] + 0.5f * wl_out[col]
                            + 0.5f * xin[o];
                    }
                    gx[o] = v;
                }
            }
        }
    }
}

// ---------------- small kernels ----------------

// ga_9 = wz_out o mask'; a1_9 = 2*u_9*ga_9 overwrites u_9 in place.
__global__ __launch_bounds__(256) void ga_init(
    const float* __restrict__ wz_out, const unsigned short* __restrict__ mask9,
    unsigned short* uh, unsigned short* ul,
    unsigned short* __restrict__ gh, unsigned short* __restrict__ gl)
{
    int i = blockIdx.x * 256 + threadIdx.x;
    int e = i << 2;
    int b = e >> 9, h = e & 511;
    unsigned short wbits = mask9[(size_t)b * 32 + (h >> 4)];
    float4 wv = *(const float4*)(wz_out + h);
    ushort4 u4h = *(const ushort4*)(uh + e);
    ushort4 u4l = *(const ushort4*)(ul + e);
    int sh = h & 15;
    ushort4 oh, ol, qh, ql;
    float f, a;
    f = wv.x * (((wbits >> (sh + 0)) & 1) ? 1.f : NS); split2(f, oh.x, ol.x);
    a = 2.f * (bf2f(u4h.x) + bf2f(u4l.x)) * f; split2(a, qh.x, ql.x);
    f = wv.y * (((wbits >> (sh + 1)) & 1) ? 1.f : NS); split2(f, oh.y, ol.y);
    a = 2.f * (bf2f(u4h.y) + bf2f(u4l.y)) * f; split2(a, qh.y, ql.y);
    f = wv.z * (((wbits >> (sh + 2)) & 1) ? 1.f : NS); split2(f, oh.z, ol.z);
    a = 2.f * (bf2f(u4h.z) + bf2f(u4l.z)) * f; split2(a, qh.z, ql.z);
    f = wv.w * (((wbits >> (sh + 3)) & 1) ? 1.f : NS); split2(f, oh.w, ol.w);
    a = 2.f * (bf2f(u4h.w) + bf2f(u4l.w)) * f; split2(a, qh.w, ql.w);
    *(ushort4*)(gh + e) = oh;
    *(ushort4*)(gl + e) = ol;
    *(ushort4*)(uh + e) = qh;
    *(ushort4*)(ul + e) = ql;
}

__global__ __launch_bounds__(256) void rowdot_kernel(
    const float* __restrict__ x, const float* __restrict__ wq_out, float* __restrict__ s) {
    const int b = blockIdx.x * 4 + (threadIdx.x >> 6);
    const int lane = threadIdx.x & 63;
    float v = x[(size_t)b * Dn + lane] * wq_out[lane] +
              x[(size_t)b * Dn + 64 + lane] * wq_out[64 + lane];
#pragma unroll
    for (int off = 32; off > 0; off >>= 1) v += __shfl_down(v, off, 64);
    if (lane == 0) s[b] = v;
}

// ---------------- launcher ----------------

extern "C" void kernel_launch(void* const* d_in, const int* in_sizes, int n_in,
                              void* d_out, int out_size, void* d_ws, size_t ws_size,
                              hipStream_t stream) {
    (void)in_sizes; (void)n_in; (void)out_size; (void)ws_size;
    const float* x      = (const float*)d_in[0];
    const float* Wq     = (const float*)d_in[1];
    const float* Wl     = (const float*)d_in[2];
    const float* bl     = (const float*)d_in[3];
    const float* Wz     = (const float*)d_in[4];
    const float* wz_out = (const float*)d_in[5];
    const float* wq_out = (const float*)d_in[6];
    const float* wl_out = (const float*)d_in[7];
    float* out = (float*)d_out;

    char* p = (char*)d_ws;
    #define CARVE(name, bytes) unsigned short* name = (unsigned short*)p; p += (((size_t)(bytes)) + 255) & ~(size_t)255;
    CARVE(xh,  (size_t)Bn*Dn*2)  CARVE(xl,  (size_t)Bn*Dn*2)
    CARVE(Wqh, (size_t)Ln*Hn*Dn*2) CARVE(Wql, (size_t)Ln*Hn*Dn*2)
    CARVE(Wlh, (size_t)Ln*Hn*Dn*2) CARVE(Wll, (size_t)Ln*Hn*Dn*2)
    CARVE(WqTh,(size_t)Ln*Hn*Dn*2) CARVE(WqTl,(size_t)Ln*Hn*Dn*2)
    CARVE(WlTh,(size_t)Ln*Hn*Dn*2) CARVE(WlTl,(size_t)Ln*Hn*Dn*2)
    CARVE(Wzh, (size_t)(Ln-1)*Hn*Hn*2) CARVE(Wzl, (size_t)(Ln-1)*Hn*Hn*2)
    CARVE(WzTh,(size_t)(Ln-1)*Hn*Hn*2) CARVE(WzTl,(size_t)(Ln-1)*Hn*Hn*2)
    CARVE(zAh, (size_t)Bn*Hn*2) CARVE(zAl, (size_t)Bn*Hn*2)
    CARVE(zBh, (size_t)Bn*Hn*2) CARVE(zBl, (size_t)Bn*Hn*2)
    CARVE(uLh, (size_t)Ln*Bn*Hn*2) CARVE(uLl, (size_t)Ln*Bn*Hn*2)   // u_l bf16 hi/lo; a1 overwrites in place
    float* s = (float*)p; p += (size_t)Bn*4;
    unsigned short* mask16 = (unsigned short*)p; p += (size_t)Ln*Bn*32*2;
    #undef CARVE

    // prep: x split + fused weight split/transpose (each weight read once)
    split_flat<<<(Bn*Dn/4 + 255)/256, 256, 0, stream>>>(x, xh, xl, Bn*Dn/4);
    split_both<<<dim3(Hn/32, Dn/32, Ln), 256, 0, stream>>>(Wq, Wqh, Wql, WqTh, WqTl, Hn, Dn);
    split_both<<<dim3(Hn/32, Dn/32, Ln), 256, 0, stream>>>(Wl, Wlh, Wll, WlTh, WlTl, Hn, Dn);
    split_both<<<dim3(Hn/32, Hn/32, Ln-1), 256, 0, stream>>>(Wz, Wzh, Wzl, WzTh, WzTl, Hn, Hn);

    rowdot_kernel<<<Bn/4, 256, 0, stream>>>(x, wq_out, s);

    const dim3 gF(Bn/128, Hn/64);  // 64 x 8

    // forward: z_l hi/lo in (l even ? zA : zB); u_l stored per layer (bf16 hi/lo)
    fwd_mfma<<<gF, 256, 0, stream>>>(xh, xl, nullptr, nullptr, nullptr, nullptr,
        Wqh, Wql, Wlh, Wll, bl, zAh, zAl, mask16, uLh, uLl, 0);
    for (int l = 1; l < Ln; ++l) {
        const unsigned short* zh  = (l & 1) ? zAh : zBh;
        const unsigned short* zl_ = (l & 1) ? zAl : zBl;
        unsigned short* oh  = (l & 1) ? zBh : zAh;
        unsigned short* ol_ = (l & 1) ? zBl : zAl;
        fwd_mfma<<<gF, 256, 0, stream>>>(xh, xl, zh, zl_,
            Wzh + (size_t)(l-1)*Hn*Hn, Wzl + (size_t)(l-1)*Hn*Hn,
            Wqh + (size_t)l*Hn*Dn, Wql + (size_t)l*Hn*Dn,
            Wlh + (size_t)l*Hn*Dn, Wll + (size_t)l*Hn*Dn,
            bl + (size_t)l*Hn, oh, ol_, mask16 + (size_t)l*Bn*32,
            uLh + (size_t)l*Bn*Hn, uLl + (size_t)l*Bn*Hn, 1);
    }

    // backward: ga_9 -> zA slots; a1_9 overwrites uL slot 9. Ping-pong downward.
    // l>0: 512 g-blocks + 128 x128-blocks = 640 (2.5/CU @ 3/CU LDS cap).
    // l=0: 256 x64-blocks.
    ga_init<<<(Bn*Hn/4)/256, 256, 0, stream>>>(wz_out, mask16 + (size_t)9*Bn*32,
        uLh + (size_t)9*Bn*Hn, uLl + (size_t)9*Bn*Hn, zAh, zAl);
    for (int l = Ln - 1; l >= 0; --l) {
        int sidx = (Ln - 1 - l) & 1;
        const unsigned short* gh_  = sidx ? zBh : zAh;
        const unsigned short* gl_  = sidx ? zBl : zAl;
        unsigned short* oh   = sidx ? zAh : zBh;
        unsigned short* ol_  = sidx ? zAl : zBl;
        const int nG = (l > 0) ? 512 : 0;
        const int nX = (l > 0) ? 128 : 256;
        bwd_combo<<<nG + nX, 256, 0, stream>>>(
            gh_, gl_,
            (l > 0) ? WzTh + (size_t)(l-1)*Hn*Hn : nullptr,
            (l > 0) ? WzTl + (size_t)(l-1)*Hn*Hn : nullptr,
            (l > 0) ? mask16 + (size_t)(l-1)*Bn*32 : nullptr,
            (l > 0) ? oh : nullptr, (l > 0) ? ol_ : nullptr,
            (l > 0) ? uLh + (size_t)(l-1)*Bn*Hn : nullptr,
            (l > 0) ? uLl + (size_t)(l-1)*Bn*Hn : nullptr,
            uLh + (size_t)l*Bn*Hn, uLl + (size_t)l*Bn*Hn,   // a1_l (in-place in uL slot l)
            WqTh + (size_t)l*Dn*Hn, WqTl + (size_t)l*Dn*Hn,
            WlTh + (size_t)l*Dn*Hn, WlTl + (size_t)l*Dn*Hn,
            out, (l == Ln - 1) ? 0 : 1, nG, (l == 0) ? 1 : 0, (l > 0) ? 1 : 0,
            x, s, wq_out, wl_out);
    }
}

// Round 8
// 850.276 us; speedup vs baseline: 1.2848x; 1.0047x over previous
//
#include <hip/hip_runtime.h>

// ICNN forward-of-gradient: out = 0.5*d(scalar)/dx + 0.5*x
// R2: all GEMMs on bf16 MFMA (16x16x32) with hi/lo split (3-product ~ fp32 accuracy).
// R3: fusion round — u stored in forward, bwd_g+bwd_x merged, final fused, prep fused.
// R5: uniform bwd blocks; a1=2u*ga computed in g-epilogue, overwrites uL in place.
// R7/R9: counted-vmcnt 2-phase; x-path merged passes. All flat at ~50us/dispatch.
// R10: diagnosis — SQ_LDS_BANK_CONFLICT 2.36M/dispatch: [R][32] tiles give 8-way
//     conflicts on ds_read_b128 fragments (16 rows x same 16B slot). Fix = T2 XOR
//     swizzle, G21 both-sides form: global source k-slot ^= (sr&3) (LDS dest linear),
//     fragment read slot ^= (lc&3). 8-way -> 4-way. Applied to fwd AND bwd.

#define Bn 8192
#define Dn 128
#define Hn 512
#define Ln 10

constexpr float NS = 0.2f;

typedef __attribute__((ext_vector_type(8))) short short8;   // 8 bf16 = 4 VGPRs (A/B frag)
typedef __attribute__((ext_vector_type(4))) float f32x4;    // C/D frag

typedef const __attribute__((address_space(1))) void GV;
typedef __attribute__((address_space(3))) void LV;

__device__ __forceinline__ void gload16(const void* g, void* l) {
    __builtin_amdgcn_global_load_lds((GV*)g, (LV*)l, 16, 0, 0);
}

template<int N> __device__ __forceinline__ void vmcnt_wait() {
    asm volatile("s_waitcnt vmcnt(%0)" :: "i"(N) : "memory");
}

#define MFMA(acc, a, b) acc = __builtin_amdgcn_mfma_f32_16x16x32_bf16(a, b, acc, 0, 0, 0)

__device__ __forceinline__ unsigned short bf16_rne(float v) {
    unsigned u = __float_as_uint(v);
    u += 0x7FFFu + ((u >> 16) & 1u);
    return (unsigned short)(u >> 16);
}
__device__ __forceinline__ float bf2f(unsigned short h) {
    return __uint_as_float(((unsigned)h) << 16);
}
__device__ __forceinline__ void split2(float v, unsigned short& h, unsigned short& l) {
    h = bf16_rne(v);
    l = bf16_rne(v - bf2f(h));
}

// ---------------- prep kernels ----------------

__global__ __launch_bounds__(256) void split_flat(const float* __restrict__ in,
        unsigned short* __restrict__ hi, unsigned short* __restrict__ lo, int n4) {
    int i = blockIdx.x * 256 + threadIdx.x;
    if (i >= n4) return;
    float4 v = ((const float4*)in)[i];
    ushort4 h, l;
    split2(v.x, h.x, l.x);
    split2(v.y, h.y, l.y);
    split2(v.z, h.z, l.z);
    split2(v.w, h.w, l.w);
    ((ushort4*)hi)[i] = h;
    ((ushort4*)lo)[i] = l;
}

// per-layer: in [R,C] fp32 -> straight split [R,C] hi/lo AND transposed split [C,R] hi/lo
__global__ __launch_bounds__(256) void split_both(const float* __restrict__ in,
        unsigned short* __restrict__ hi, unsigned short* __restrict__ lo,
        unsigned short* __restrict__ thi, unsigned short* __restrict__ tlo,
        int R, int C) {
    __shared__ float t[32][33];
    const size_t off = (size_t)blockIdx.z * R * C;
    const float* src = in + off;
    unsigned short* sh_ = hi + off;
    unsigned short* sl_ = lo + off;
    unsigned short* dh = thi + off;
    unsigned short* dl = tlo + off;
    const int r0 = blockIdx.x * 32, c0 = blockIdx.y * 32;
    const int tr = threadIdx.x >> 5, tc = threadIdx.x & 31;
#pragma unroll
    for (int i = 0; i < 4; ++i) {
        size_t si = (size_t)(r0 + tr + 8 * i) * C + c0 + tc;
        float v = src[si];
        t[tr + 8 * i][tc] = v;
        unsigned short h, l; split2(v, h, l);
        sh_[si] = h; sl_[si] = l;
    }
    __syncthreads();
#pragma unroll
    for (int i = 0; i < 4; ++i) {
        float v = t[tc][tr + 8 * i];
        unsigned short h, l; split2(v, h, l);
        size_t o = (size_t)(c0 + tr + 8 * i) * R + r0 + tc;
        dh[o] = h; dl[o] = l;
    }
}

// ---------------- fwd layer: 128x64 tile, NT, 3-product split ----------------
// LDS tiles swizzled: cell (row, slot) holds global k-slot (slot ^ (row&3)).

__global__ __launch_bounds__(256) void fwd_mfma(
    const unsigned short* __restrict__ xh, const unsigned short* __restrict__ xl,
    const unsigned short* __restrict__ zph, const unsigned short* __restrict__ zpl,
    const unsigned short* __restrict__ Wzh, const unsigned short* __restrict__ Wzl,
    const unsigned short* __restrict__ Wqh, const unsigned short* __restrict__ Wql,
    const unsigned short* __restrict__ Wlh, const unsigned short* __restrict__ Wll,
    const float* __restrict__ bl,
    unsigned short* __restrict__ zoh, unsigned short* __restrict__ zol,
    unsigned short* __restrict__ mask16,
    unsigned short* __restrict__ uoh, unsigned short* __restrict__ uol, int hasZ)
{
    __shared__ __align__(16) char smem[32768];
    unsigned short* Ah  = (unsigned short*)smem;            // [128][32]
    unsigned short* Al  = (unsigned short*)(smem + 8192);
    unsigned short* B0h = (unsigned short*)(smem + 16384);  // [64][32]
    unsigned short* B0l = (unsigned short*)(smem + 20480);
    unsigned short* B1h = (unsigned short*)(smem + 24576);
    unsigned short* B1l = (unsigned short*)(smem + 28672);

    const int tid = threadIdx.x;
    const int w = tid >> 6, lane = tid & 63;
    const int lq = lane >> 4, lc = lane & 15;
    const int wm = (w & 1) * 64, wn = (w >> 1) * 32;
    const int row0 = blockIdx.x * 128, col0 = blockIdx.y * 64;
    const int sr = lane >> 2;
    const int sks = (((lane & 3) ^ (sr & 3)) * 8);   // swizzled source k-slot
    const int q8 = ((lq ^ (lc & 3)) * 8);            // swizzled read slot

    f32x4 accz[4][2], accu[4][2], accv[4][2];
#pragma unroll
    for (int i = 0; i < 4; ++i)
#pragma unroll
        for (int j = 0; j < 2; ++j)
#pragma unroll
            for (int r = 0; r < 4; ++r) { accz[i][j][r] = 0.f; accu[i][j][r] = 0.f; accv[i][j][r] = 0.f; }

    if (hasZ) {
        for (int k0 = 0; k0 < Hn; k0 += 32) {
            __syncthreads();
            for (int c = w; c < 8; c += 4) {
                size_t go = (size_t)(row0 + c * 16 + sr) * Hn + k0 + sks;
                gload16(zph + go, Ah + c * 512);
                gload16(zpl + go, Al + c * 512);
            }
            {
                int c = w;
                size_t go = (size_t)(col0 + c * 16 + sr) * Hn + k0 + sks;
                gload16(Wzh + go, B0h + c * 512);
                gload16(Wzl + go, B0l + c * 512);
            }
            __syncthreads();
            short8 ah[4], al[4];
#pragma unroll
            for (int mt = 0; mt < 4; ++mt) {
                int ao = (wm + mt * 16 + lc) * 32 + q8;
                ah[mt] = *(const short8*)(Ah + ao);
                al[mt] = *(const short8*)(Al + ao);
            }
#pragma unroll
            for (int nt = 0; nt < 2; ++nt) {
                int bo = (wn + nt * 16 + lc) * 32 + q8;
                short8 bh = *(const short8*)(B0h + bo);
                short8 bv = *(const short8*)(B0l + bo);
#pragma unroll
                for (int mt = 0; mt < 4; ++mt) {
                    MFMA(accz[mt][nt], ah[mt], bh);
                    MFMA(accz[mt][nt], ah[mt], bv);
                    MFMA(accz[mt][nt], al[mt], bh);
                }
            }
        }
    }

    for (int k0 = 0; k0 < Dn; k0 += 32) {
        __syncthreads();
        for (int c = w; c < 8; c += 4) {
            size_t go = (size_t)(row0 + c * 16 + sr) * Dn + k0 + sks;
            gload16(xh + go, Ah + c * 512);
            gload16(xl + go, Al + c * 512);
        }
        {
            int c = w;
            size_t go = (size_t)(col0 + c * 16 + sr) * Dn + k0 + sks;
            gload16(Wqh + go, B0h + c * 512);
            gload16(Wql + go, B0l + c * 512);
            gload16(Wlh + go, B1h + c * 512);
            gload16(Wll + go, B1l + c * 512);
        }
        __syncthreads();
        short8 ah[4], al[4];
#pragma unroll
        for (int mt = 0; mt < 4; ++mt) {
            int ao = (wm + mt * 16 + lc) * 32 + q8;
            ah[mt] = *(const short8*)(Ah + ao);
            al[mt] = *(const short8*)(Al + ao);
        }
#pragma unroll
        for (int nt = 0; nt < 2; ++nt) {
            int bo = (wn + nt * 16 + lc) * 32 + q8;
            short8 bqh = *(const short8*)(B0h + bo);
            short8 bql = *(const short8*)(B0l + bo);
            short8 blh = *(const short8*)(B1h + bo);
            short8 bll = *(const short8*)(B1l + bo);
#pragma unroll
            for (int mt = 0; mt < 4; ++mt) {
                MFMA(accu[mt][nt], ah[mt], bqh);
                MFMA(accu[mt][nt], ah[mt], bql);
                MFMA(accu[mt][nt], al[mt], bqh);
                MFMA(accv[mt][nt], ah[mt], blh);
                MFMA(accv[mt][nt], ah[mt], bll);
                MFMA(accv[mt][nt], al[mt], blh);
            }
        }
    }

#pragma unroll
    for (int nt = 0; nt < 2; ++nt) {
        const int colb = col0 + wn + nt * 16;
        const int col = colb + lc;
        const float blv = bl[col];
#pragma unroll
        for (int mt = 0; mt < 4; ++mt) {
            const int rowb = row0 + wm + mt * 16;
#pragma unroll
            for (int r = 0; r < 4; ++r) {
                float uq = accu[mt][nt][r];
                float pre = accz[mt][nt][r] + uq * uq + accv[mt][nt][r] + blv;
                bool m = pre >= 0.f;
                unsigned long long bal = __ballot(m);
                if (lc == 0) {
                    int rw = rowb + lq * 4 + r;
                    mask16[(size_t)rw * 32 + (colb >> 4)] =
                        (unsigned short)((bal >> (lq * 16)) & 0xFFFFull);
                }
                float zv = m ? pre : NS * pre;
                unsigned short h, l; split2(zv, h, l);
                size_t o = (size_t)(rowb + lq * 4 + r) * Hn + col;
                zoh[o] = h; zol[o] = l;
                unsigned short uhh, ull; split2(uq, uhh, ull);
                uoh[o] = uhh; uol[o] = ull;
            }
        }
    }
}

// ---------------- merged backward layer kernel (counted-vmcnt 2-phase, swizzled) ----------------

__global__ __launch_bounds__(256) void bwd_combo(
    const unsigned short* __restrict__ gah, const unsigned short* __restrict__ gal,
    const unsigned short* __restrict__ WzTh, const unsigned short* __restrict__ WzTl,
    const unsigned short* __restrict__ maskprev,
    unsigned short* __restrict__ goh, unsigned short* __restrict__ gol,
    unsigned short* uph, unsigned short* upl,           // u_{l-1} in, a1_{l-1} out (in place)
    const unsigned short* __restrict__ a1h_, const unsigned short* __restrict__ a1l_,
    const unsigned short* __restrict__ WqTh, const unsigned short* __restrict__ WqTl,
    const unsigned short* __restrict__ WlTh, const unsigned short* __restrict__ WlTl,
    float* __restrict__ gx, int addTo, int nG, int finalF, int x128,
    const float* __restrict__ xin, const float* __restrict__ s,
    const float* __restrict__ wq_out, const float* __restrict__ wl_out)
{
    __shared__ __align__(16) char smem[49152];
    const int bid = blockIdx.x;
    const int tid = threadIdx.x;
    const int w = tid >> 6, lane = tid & 63;
    const int lq = lane >> 4, lc = lane & 15;
    const int sr = lane >> 2;
    const int sks = (((lane & 3) ^ (sr & 3)) * 8);   // swizzled source k-slot
    const int q8 = ((lq ^ (lc & 3)) * 8);            // swizzled read slot

    if (bid < nG) {
        // ---------- g path: 128x64, dbuf 2x24KB, 6 loads/thread/iter ----------
        const int wm = (w & 1) * 64, wn = (w >> 1) * 32;
        const int row0 = (bid & 63) * 128, col0 = (bid >> 6) * 64;

        f32x4 acc[4][2];
#pragma unroll
        for (int i = 0; i < 4; ++i)
#pragma unroll
            for (int j = 0; j < 2; ++j)
#pragma unroll
                for (int r = 0; r < 4; ++r) acc[i][j][r] = 0.f;

        // buffer (24KB): Ah[128][32] 8K, Al 8K, Bh[64][32] 4K, Bl 4K
        auto STAGE = [&](int buf, int k0) {
            char* base = smem + buf * 24576;
            unsigned short* Ah = (unsigned short*)base;
            unsigned short* Al = (unsigned short*)(base + 8192);
            unsigned short* Bh = (unsigned short*)(base + 16384);
            unsigned short* Bl = (unsigned short*)(base + 20480);
#pragma unroll
            for (int c0c = 0; c0c < 2; ++c0c) {
                int c = w + c0c * 4;
                size_t go = (size_t)(row0 + c * 16 + sr) * Hn + k0 + sks;
                gload16(gah + go, Ah + c * 512);
                gload16(gal + go, Al + c * 512);
            }
            {
                int c = w;
                size_t go = (size_t)(col0 + c * 16 + sr) * Hn + k0 + sks;
                gload16(WzTh + go, Bh + c * 512);
                gload16(WzTl + go, Bl + c * 512);
            }
        };

        STAGE(0, 0);                       // 6 loads in flight
        int cur = 0;
        for (int it = 0; it < 16; ++it) {
            if (it < 15) {
                STAGE(cur ^ 1, (it + 1) * 32);   // +6 loads (next buffer)
                vmcnt_wait<6>();                  // oldest 6 (cur buffer) landed
            } else {
                vmcnt_wait<0>();
            }
            __builtin_amdgcn_sched_barrier(0);
            __builtin_amdgcn_s_barrier();         // cur buffer valid for all waves
            __builtin_amdgcn_sched_barrier(0);
            const char* base = smem + cur * 24576;
            const unsigned short* Ah = (const unsigned short*)base;
            const unsigned short* Al = (const unsigned short*)(base + 8192);
            const unsigned short* Bh = (const unsigned short*)(base + 16384);
            const unsigned short* Bl = (const unsigned short*)(base + 20480);
            short8 ah[4], al[4];
#pragma unroll
            for (int mt = 0; mt < 4; ++mt) {
                int ao = (wm + mt * 16 + lc) * 32 + q8;
                ah[mt] = *(const short8*)(Ah + ao);
                al[mt] = *(const short8*)(Al + ao);
            }
#pragma unroll
            for (int nt = 0; nt < 2; ++nt) {
                int bo = (wn + nt * 16 + lc) * 32 + q8;
                short8 bh = *(const short8*)(Bh + bo);
                short8 bv = *(const short8*)(Bl + bo);
#pragma unroll
                for (int mt = 0; mt < 4; ++mt) {
                    MFMA(acc[mt][nt], ah[mt], bh);
                    MFMA(acc[mt][nt], ah[mt], bv);
                    MFMA(acc[mt][nt], al[mt], bh);
                }
            }
            __builtin_amdgcn_s_barrier();         // reads of cur done; next STAGE may overwrite
            cur ^= 1;
        }

#pragma unroll
        for (int nt = 0; nt < 2; ++nt) {
            const int colb = col0 + wn + nt * 16;
            const int col = colb + lc;
#pragma unroll
            for (int mt = 0; mt < 4; ++mt) {
                const int rowb = row0 + wm + mt * 16;
#pragma unroll
                for (int r = 0; r < 4; ++r) {
                    int row = rowb + lq * 4 + r;
                    unsigned short wbits = maskprev[(size_t)row * 32 + (colb >> 4)];
                    float f = ((wbits >> lc) & 1) ? 1.f : NS;
                    float v = acc[mt][nt][r] * f;
                    unsigned short h, l; split2(v, h, l);
                    size_t o = (size_t)row * Hn + col;
                    goh[o] = h; gol[o] = l;
                    // a1_{l-1} = 2 * u_{l-1} * ga_{l-1}; overwrite u in place (dead after)
                    float uv = bf2f(uph[o]) + bf2f(upl[o]);
                    float a1v = 2.f * uv * v;
                    unsigned short h2, l2; split2(a1v, h2, l2);
                    uph[o] = h2; upl[o] = l2;
                }
            }
        }
    } else if (x128) {
        // ---------- x path (l>0): 128x64, merged passes, dbuf 2x24KB, 6 loads/iter ----------
        const int wm = (w & 1) * 64, wn = (w >> 1) * 32;
        const int t = bid - nG;
        const int row0 = (t >> 1) * 128, col0 = (t & 1) * 64;

        f32x4 acc[4][2];
#pragma unroll
        for (int i = 0; i < 4; ++i)
#pragma unroll
            for (int j = 0; j < 2; ++j)
#pragma unroll
                for (int r = 0; r < 4; ++r) acc[i][j][r] = 0.f;

        // buffer (24KB): Ah[128][32] 8K, Al 8K, Bh[64][32] 4K, Bl 4K
        auto STAGE = [&](int buf, int j) {
            const int pass = j >> 4, k0 = (j & 15) * 32;
            const unsigned short* Ash = pass ? gah : a1h_;
            const unsigned short* Asl = pass ? gal : a1l_;
            const unsigned short* Bsh = pass ? WlTh : WqTh;
            const unsigned short* Bsl = pass ? WlTl : WqTl;
            char* base = smem + buf * 24576;
            unsigned short* Ah = (unsigned short*)base;
            unsigned short* Al = (unsigned short*)(base + 8192);
            unsigned short* Bh = (unsigned short*)(base + 16384);
            unsigned short* Bl = (unsigned short*)(base + 20480);
#pragma unroll
            for (int c0c = 0; c0c < 2; ++c0c) {
                int c = w + c0c * 4;
                size_t ga_ = (size_t)(row0 + c * 16 + sr) * Hn + k0 + sks;
                gload16(Ash + ga_, Ah + c * 512);
                gload16(Asl + ga_, Al + c * 512);
            }
            {
                int c = w;
                size_t gb_ = (size_t)(col0 + c * 16 + sr) * Hn + k0 + sks;
                gload16(Bsh + gb_, Bh + c * 512);
                gload16(Bsl + gb_, Bl + c * 512);
            }
        };

        STAGE(0, 0);
        int cur = 0;
        for (int j = 0; j < 32; ++j) {
            if (j < 31) {
                STAGE(cur ^ 1, j + 1);
                vmcnt_wait<6>();
            } else {
                vmcnt_wait<0>();
            }
            __builtin_amdgcn_sched_barrier(0);
            __builtin_amdgcn_s_barrier();
            __builtin_amdgcn_sched_barrier(0);
            const char* base = smem + cur * 24576;
            const unsigned short* Ah = (const unsigned short*)base;
            const unsigned short* Al = (const unsigned short*)(base + 8192);
            const unsigned short* Bh = (const unsigned short*)(base + 16384);
            const unsigned short* Bl = (const unsigned short*)(base + 20480);
            short8 ah[4], al[4];
#pragma unroll
            for (int mt = 0; mt < 4; ++mt) {
                int ao = (wm + mt * 16 + lc) * 32 + q8;
                ah[mt] = *(const short8*)(Ah + ao);
                al[mt] = *(const short8*)(Al + ao);
            }
#pragma unroll
            for (int nt = 0; nt < 2; ++nt) {
                int bo = (wn + nt * 16 + lc) * 32 + q8;
                short8 bh = *(const short8*)(Bh + bo);
                short8 bv = *(const short8*)(Bl + bo);
#pragma unroll
                for (int mt = 0; mt < 4; ++mt) {
                    MFMA(acc[mt][nt], ah[mt], bh);
                    MFMA(acc[mt][nt], ah[mt], bv);
                    MFMA(acc[mt][nt], al[mt], bh);
                }
            }
            __builtin_amdgcn_s_barrier();
            cur ^= 1;
        }

#pragma unroll
        for (int nt = 0; nt < 2; ++nt) {
            const int col = col0 + wn + nt * 16 + lc;
#pragma unroll
            for (int mt = 0; mt < 4; ++mt) {
                const int rowb = row0 + wm + mt * 16;
#pragma unroll
                for (int r = 0; r < 4; ++r) {
                    const int row = rowb + lq * 4 + r;
                    size_t o = (size_t)row * Dn + col;
                    float v = acc[mt][nt][r];
                    if (addTo) v += gx[o];
                    if (finalF) {
                        v = 0.5f * v + s[row] * wq_out[col] + 0.5f * wl_out[col]
                            + 0.5f * xin[o];
                    }
                    gx[o] = v;
                }
            }
        }
    } else {
        // ---------- x path (l=0): 64x64, merged passes, dbuf 2x16KB, 4 loads/iter ----------
        const int wm = (w & 1) * 32, wn = (w >> 1) * 32;
        const int t = bid - nG;
        const int row0 = (t >> 1) * 64, col0 = (t & 1) * 64;

        f32x4 acc[2][2];
#pragma unroll
        for (int i = 0; i < 2; ++i)
#pragma unroll
            for (int j = 0; j < 2; ++j)
#pragma unroll
                for (int r = 0; r < 4; ++r) acc[i][j][r] = 0.f;

        // buffer (16KB): Ah[64][32] 4K, Al 4K, Bh[64][32] 4K, Bl 4K
        auto STAGE = [&](int buf, int j) {
            int pass = j >> 4, k0 = (j & 15) * 32;
            const unsigned short* Ash = pass ? gah : a1h_;
            const unsigned short* Asl = pass ? gal : a1l_;
            const unsigned short* Bsh = pass ? WlTh : WqTh;
            const unsigned short* Bsl = pass ? WlTl : WqTl;
            char* base = smem + buf * 16384;
            unsigned short* Ah = (unsigned short*)base;
            unsigned short* Al = (unsigned short*)(base + 4096);
            unsigned short* Bh = (unsigned short*)(base + 8192);
            unsigned short* Bl = (unsigned short*)(base + 12288);
            int c = w;
            size_t ga_ = (size_t)(row0 + c * 16 + sr) * Hn + k0 + sks;
            gload16(Ash + ga_, Ah + c * 512);
            gload16(Asl + ga_, Al + c * 512);
            size_t gb_ = (size_t)(col0 + c * 16 + sr) * Hn + k0 + sks;
            gload16(Bsh + gb_, Bh + c * 512);
            gload16(Bsl + gb_, Bl + c * 512);
        };

        STAGE(0, 0);
        int cur = 0;
        for (int j = 0; j < 32; ++j) {
            if (j < 31) {
                STAGE(cur ^ 1, j + 1);
                vmcnt_wait<4>();
            } else {
                vmcnt_wait<0>();
            }
            __builtin_amdgcn_sched_barrier(0);
            __builtin_amdgcn_s_barrier();
            __builtin_amdgcn_sched_barrier(0);
            const char* base = smem + cur * 16384;
            const unsigned short* Ah = (const unsigned short*)base;
            const unsigned short* Al = (const unsigned short*)(base + 4096);
            const unsigned short* Bh = (const unsigned short*)(base + 8192);
            const unsigned short* Bl = (const unsigned short*)(base + 12288);
            short8 ah[2], al[2];
#pragma unroll
            for (int mt = 0; mt < 2; ++mt) {
                int ao = (wm + mt * 16 + lc) * 32 + q8;
                ah[mt] = *(const short8*)(Ah + ao);
                al[mt] = *(const short8*)(Al + ao);
            }
#pragma unroll
            for (int nt = 0; nt < 2; ++nt) {
                int bo = (wn + nt * 16 + lc) * 32 + q8;
                short8 bh = *(const short8*)(Bh + bo);
                short8 bv = *(const short8*)(Bl + bo);
#pragma unroll
                for (int mt = 0; mt < 2; ++mt) {
                    MFMA(acc[mt][nt], ah[mt], bh);
                    MFMA(acc[mt][nt], ah[mt], bv);
                    MFMA(acc[mt][nt], al[mt], bh);
                }
            }
            __builtin_amdgcn_s_barrier();
            cur ^= 1;
        }

#pragma unroll
        for (int nt = 0; nt < 2; ++nt) {
            const int col = col0 + wn + nt * 16 + lc;
#pragma unroll
            for (int mt = 0; mt < 2; ++mt) {
                const int rowb = row0 + wm + mt * 16;
#pragma unroll
                for (int r = 0; r < 4; ++r) {
                    const int row = rowb + lq * 4 + r;
                    size_t o = (size_t)row * Dn + col;
                    float v = acc[mt][nt][r];
                    if (addTo) v += gx[o];
                    if (finalF) {
                        v = 0.5f * v + s[row] * wq_out[col] + 0.5f * wl_out[col]
                            + 0.5f * xin[o];
                    }
                    gx[o] = v;
                }
            }
        }
    }
}

// ---------------- small kernels ----------------

// ga_9 = wz_out o mask'; a1_9 = 2*u_9*ga_9 overwrites u_9 in place.
__global__ __launch_bounds__(256) void ga_init(
    const float* __restrict__ wz_out, const unsigned short* __restrict__ mask9,
    unsigned short* uh, unsigned short* ul,
    unsigned short* __restrict__ gh, unsigned short* __restrict__ gl)
{
    int i = blockIdx.x * 256 + threadIdx.x;
    int e = i << 2;
    int b = e >> 9, h = e & 511;
    unsigned short wbits = mask9[(size_t)b * 32 + (h >> 4)];
    float4 wv = *(const float4*)(wz_out + h);
    ushort4 u4h = *(const ushort4*)(uh + e);
    ushort4 u4l = *(const ushort4*)(ul + e);
    int sh = h & 15;
    ushort4 oh, ol, qh, ql;
    float f, a;
    f = wv.x * (((wbits >> (sh + 0)) & 1) ? 1.f : NS); split2(f, oh.x, ol.x);
    a = 2.f * (bf2f(u4h.x) + bf2f(u4l.x)) * f; split2(a, qh.x, ql.x);
    f = wv.y * (((wbits >> (sh + 1)) & 1) ? 1.f : NS); split2(f, oh.y, ol.y);
    a = 2.f * (bf2f(u4h.y) + bf2f(u4l.y)) * f; split2(a, qh.y, ql.y);
    f = wv.z * (((wbits >> (sh + 2)) & 1) ? 1.f : NS); split2(f, oh.z, ol.z);
    a = 2.f * (bf2f(u4h.z) + bf2f(u4l.z)) * f; split2(a, qh.z, ql.z);
    f = wv.w * (((wbits >> (sh + 3)) & 1) ? 1.f : NS); split2(f, oh.w, ol.w);
    a = 2.f * (bf2f(u4h.w) + bf2f(u4l.w)) * f; split2(a, qh.w, ql.w);
    *(ushort4*)(gh + e) = oh;
    *(ushort4*)(gl + e) = ol;
    *(ushort4*)(uh + e) = qh;
    *(ushort4*)(ul + e) = ql;
}

__global__ __launch_bounds__(256) void rowdot_kernel(
    const float* __restrict__ x, const float* __restrict__ wq_out, float* __restrict__ s) {
    const int b = blockIdx.x * 4 + (threadIdx.x >> 6);
    const int lane = threadIdx.x & 63;
    float v = x[(size_t)b * Dn + lane] * wq_out[lane] +
              x[(size_t)b * Dn + 64 + lane] * wq_out[64 + lane];
#pragma unroll
    for (int off = 32; off > 0; off >>= 1) v += __shfl_down(v, off, 64);
    if (lane == 0) s[b] = v;
}

// ---------------- launcher ----------------

extern "C" void kernel_launch(void* const* d_in, const int* in_sizes, int n_in,
                              void* d_out, int out_size, void* d_ws, size_t ws_size,
                              hipStream_t stream) {
    (void)in_sizes; (void)n_in; (void)out_size; (void)ws_size;
    const float* x      = (const float*)d_in[0];
    const float* Wq     = (const float*)d_in[1];
    const float* Wl     = (const float*)d_in[2];
    const float* bl     = (const float*)d_in[3];
    const float* Wz     = (const float*)d_in[4];
    const float* wz_out = (const float*)d_in[5];
    const float* wq_out = (const float*)d_in[6];
    const float* wl_out = (const float*)d_in[7];
    float* out = (float*)d_out;

    char* p = (char*)d_ws;
    #define CARVE(name, bytes) unsigned short* name = (unsigned short*)p; p += (((size_t)(bytes)) + 255) & ~(size_t)255;
    CARVE(xh,  (size_t)Bn*Dn*2)  CARVE(xl,  (size_t)Bn*Dn*2)
    CARVE(Wqh, (size_t)Ln*Hn*Dn*2) CARVE(Wql, (size_t)Ln*Hn*Dn*2)
    CARVE(Wlh, (size_t)Ln*Hn*Dn*2) CARVE(Wll, (size_t)Ln*Hn*Dn*2)
    CARVE(WqTh,(size_t)Ln*Hn*Dn*2) CARVE(WqTl,(size_t)Ln*Hn*Dn*2)
    CARVE(WlTh,(size_t)Ln*Hn*Dn*2) CARVE(WlTl,(size_t)Ln*Hn*Dn*2)
    CARVE(Wzh, (size_t)(Ln-1)*Hn*Hn*2) CARVE(Wzl, (size_t)(Ln-1)*Hn*Hn*2)
    CARVE(WzTh,(size_t)(Ln-1)*Hn*Hn*2) CARVE(WzTl,(size_t)(Ln-1)*Hn*Hn*2)
    CARVE(zAh, (size_t)Bn*Hn*2) CARVE(zAl, (size_t)Bn*Hn*2)
    CARVE(zBh, (size_t)Bn*Hn*2) CARVE(zBl, (size_t)Bn*Hn*2)
    CARVE(uLh, (size_t)Ln*Bn*Hn*2) CARVE(uLl, (size_t)Ln*Bn*Hn*2)   // u_l bf16 hi/lo; a1 overwrites in place
    float* s = (float*)p; p += (size_t)Bn*4;
    unsigned short* mask16 = (unsigned short*)p; p += (size_t)Ln*Bn*32*2;
    #undef CARVE

    // prep: x split + fused weight split/transpose (each weight read once)
    split_flat<<<(Bn*Dn/4 + 255)/256, 256, 0, stream>>>(x, xh, xl, Bn*Dn/4);
    split_both<<<dim3(Hn/32, Dn/32, Ln), 256, 0, stream>>>(Wq, Wqh, Wql, WqTh, WqTl, Hn, Dn);
    split_both<<<dim3(Hn/32, Dn/32, Ln), 256, 0, stream>>>(Wl, Wlh, Wll, WlTh, WlTl, Hn, Dn);
    split_both<<<dim3(Hn/32, Hn/32, Ln-1), 256, 0, stream>>>(Wz, Wzh, Wzl, WzTh, WzTl, Hn, Hn);

    rowdot_kernel<<<Bn/4, 256, 0, stream>>>(x, wq_out, s);

    const dim3 gF(Bn/128, Hn/64);  // 64 x 8

    // forward: z_l hi/lo in (l even ? zA : zB); u_l stored per layer (bf16 hi/lo)
    fwd_mfma<<<gF, 256, 0, stream>>>(xh, xl, nullptr, nullptr, nullptr, nullptr,
        Wqh, Wql, Wlh, Wll, bl, zAh, zAl, mask16, uLh, uLl, 0);
    for (int l = 1; l < Ln; ++l) {
        const unsigned short* zh  = (l & 1) ? zAh : zBh;
        const unsigned short* zl_ = (l & 1) ? zAl : zBl;
        unsigned short* oh  = (l & 1) ? zBh : zAh;
        unsigned short* ol_ = (l & 1) ? zBl : zAl;
        fwd_mfma<<<gF, 256, 0, stream>>>(xh, xl, zh, zl_,
            Wzh + (size_t)(l-1)*Hn*Hn, Wzl + (size_t)(l-1)*Hn*Hn,
            Wqh + (size_t)l*Hn*Dn, Wql + (size_t)l*Hn*Dn,
            Wlh + (size_t)l*Hn*Dn, Wll + (size_t)l*Hn*Dn,
            bl + (size_t)l*Hn, oh, ol_, mask16 + (size_t)l*Bn*32,
            uLh + (size_t)l*Bn*Hn, uLl + (size_t)l*Bn*Hn, 1);
    }

    // backward: ga_9 -> zA slots; a1_9 overwrites uL slot 9. Ping-pong downward.
    // l>0: 512 g-blocks + 128 x128-blocks = 640. l=0: 256 x64-blocks.
    ga_init<<<(Bn*Hn/4)/256, 256, 0, stream>>>(wz_out, mask16 + (size_t)9*Bn*32,
        uLh + (size_t)9*Bn*Hn, uLl + (size_t)9*Bn*Hn, zAh, zAl);
    for (int l = Ln - 1; l >= 0; --l) {
        int sidx = (Ln - 1 - l) & 1;
        const unsigned short* gh_  = sidx ? zBh : zAh;
        const unsigned short* gl_  = sidx ? zBl : zAl;
        unsigned short* oh   = sidx ? zAh : zBh;
        unsigned short* ol_  = sidx ? zAl : zBl;
        const int nG = (l > 0) ? 512 : 0;
        const int nX = (l > 0) ? 128 : 256;
        bwd_combo<<<nG + nX, 256, 0, stream>>>(
            gh_, gl_,
            (l > 0) ? WzTh + (size_t)(l-1)*Hn*Hn : nullptr,
            (l > 0) ? WzTl + (size_t)(l-1)*Hn*Hn : nullptr,
            (l > 0) ? mask16 + (size_t)(l-1)*Bn*32 : nullptr,
            (l > 0) ? oh : nullptr, (l > 0) ? ol_ : nullptr,
            (l > 0) ? uLh + (size_t)(l-1)*Bn*Hn : nullptr,
            (l > 0) ? uLl + (size_t)(l-1)*Bn*Hn : nullptr,
            uLh + (size_t)l*Bn*Hn, uLl + (size_t)l*Bn*Hn,   // a1_l (in-place in uL slot l)
            WqTh + (size_t)l*Dn*Hn, WqTl + (size_t)l*Dn*Hn,
            WlTh + (size_t)l*Dn*Hn, WlTl + (size_t)l*Dn*Hn,
            out, (l == Ln - 1) ? 0 : 1, nG, (l == 0) ? 1 : 0, (l > 0) ? 1 : 0,
            x, s, wq_out, wl_out);
    }
}